// Round 5
// baseline (12630.906 us; speedup 1.0000x reference)
//
#include <hip/hip_runtime.h>
#include <cstdint>
#include <cstddef>

// ---------------------------------------------------------------------------
// Trainer_91216515433187: BN + Dense + LSTM encoder (1024 steps) + 35-step
// autoregressive LSTM decoder.
//
// Round 6: back to the fully register-resident weight topology (R1) with a
// re-engineered cross-WG exchange. 32 WGs = 16 batch-tiles x 2 hidden-halves;
// each WG holds its 512 output cols' recurrent weights entirely in registers
// (8 K-slots x 4 gates x 4 VGPR = 128/thread) -> ZERO per-step weight traffic.
// Per step: own h-half lives in LDS (parity dbuf, chunk-transposed,
// conflict-free b128); partner h-half (4 KB) goes through L2: plain stores +
// one release flag store (tid0, after one __syncthreads), partner waves poll
// independently with acquire loads and read A-frags straight global->regs.
// ONE barrier per step. Decoder pred reuses the step's A-frags; token
// redistributed via __shfl; Deff/dbias folded into acc-init (VALU).
// Pairs (bid, bid+16) land same-XCD under %8 round-robin (heuristic only;
// agent-scope release/acquire gives correctness regardless).
// ---------------------------------------------------------------------------

typedef _Float16 h8 __attribute__((ext_vector_type(8)));
typedef float f4 __attribute__((ext_vector_type(4)));

// ws byte offsets
#define WS_FLAGS  0         // 16 tiles x 2 halves x 16 u32 (64B stride) = 2048
#define WS_HBUF   2048      // 2 par x 16 tiles x 2 halves x (16r x 128c) f16 = 262144
#define WS_RKT    264192    // 1024 cols x 256 k f16 = 524288
#define WS_WEFF   788480    // 1024 cols x 8 f f16 = 16384
#define WS_WMLP   804864    // 2 e x 256 k f16 = 1024
#define WS_DEFF   805888    // f32 [2][1024] = 8192
#define WS_ZB     814080    // 1024 f32
#define WS_DB     818176    // 1024 f32  -> end 822272

__device__ __forceinline__ float fexp2(float x){
#if __has_builtin(__builtin_amdgcn_exp2f)
  return __builtin_amdgcn_exp2f(x);
#else
  return exp2f(x);
#endif
}
__device__ __forceinline__ float frcp(float x){
#if __has_builtin(__builtin_amdgcn_rcpf)
  return __builtin_amdgcn_rcpf(x);
#else
  return 1.f / x;
#endif
}
__device__ __forceinline__ float sigf(float x){
  return frcp(1.f + fexp2(-1.44269504f * x));
}
__device__ __forceinline__ float tanh_f(float x){
  return 2.f * frcp(1.f + fexp2(-2.88539008f * x)) - 1.f;
}

__global__ void zero_ws_k(uint32_t* __restrict__ p, int nw){
  int i = blockIdx.x * 256 + threadIdx.x;
  if (i < nw) p[i] = 0u;
}

// grid 1024 x 256 threads (known-correct from round 1)
__global__ void precompute_k(const float* __restrict__ bn_gamma,
                             const float* __restrict__ bn_beta,
                             const float* __restrict__ bn_mean,
                             const float* __restrict__ bn_var,
                             const float* __restrict__ W_pulse,   // (8,256)
                             const float* __restrict__ b_pulse,   // (256)
                             const float* __restrict__ lstm_k,    // (256,1024)
                             const float* __restrict__ lstm_rk,   // (256,1024)
                             const float* __restrict__ lstm_b,    // (1024)
                             const float* __restrict__ W_eis,     // (2,256)
                             const float* __restrict__ b_eis,     // (256)
                             const float* __restrict__ W_mlp,     // (256,2)
                             _Float16* __restrict__ rkT,          // [col][k]
                             _Float16* __restrict__ WeffT,        // [col][f]
                             _Float16* __restrict__ WmlpT,        // [e][k]
                             float* __restrict__ Deff,            // [e][col]
                             float* __restrict__ zbias,
                             float* __restrict__ dbias)
{
  int gid = blockIdx.x * 256 + threadIdx.x;   // 0..262143
  {
    int col = gid >> 8;
    int k   = gid & 255;
    rkT[col * 256 + k] = (_Float16)lstm_rk[k * 1024 + col];
  }
  if (gid < 512) {
    int e = gid >> 8, k = gid & 255;
    WmlpT[e * 256 + k] = (_Float16)W_mlp[k * 2 + e];
  }
  if (gid < 1024) {
    int j = gid;
    float a[8], bv[8];
#pragma unroll
    for (int f = 0; f < 8; ++f) {
      float af = bn_gamma[f] * rsqrtf(bn_var[f] + 1e-3f);
      a[f]  = af;
      bv[f] = bn_beta[f] - bn_mean[f] * af;
    }
    float m[8] = {0,0,0,0,0,0,0,0};
    float d0 = 0.f, d1 = 0.f, zb2 = 0.f, db2 = 0.f;
    for (int k = 0; k < 256; ++k) {
      float lk = lstm_k[k * 1024 + j];
#pragma unroll
      for (int f = 0; f < 8; ++f) m[f] += W_pulse[f * 256 + k] * lk;
      d0  += W_eis[k]       * lk;
      d1  += W_eis[256 + k] * lk;
      zb2 += b_pulse[k] * lk;
      db2 += b_eis[k]   * lk;
    }
    float zb = lstm_b[j] + zb2;
#pragma unroll
    for (int f = 0; f < 8; ++f) {
      zb += bv[f] * m[f];
      WeffT[j * 8 + f] = (_Float16)(a[f] * m[f]);
    }
    zbias[j] = zb;
    dbias[j] = lstm_b[j] + db2;
    Deff[j]        = d0;
    Deff[1024 + j] = d1;
  }
}

// poll partner flag (wave-uniform; acquire makes partner h visible)
#define POLL(wantT)                                                            \
  while (__hip_atomic_load(flagPa, __ATOMIC_ACQUIRE,                           \
                           __HIP_MEMORY_SCOPE_AGENT) < (uint32_t)(wantT))      \
    __builtin_amdgcn_s_sleep(1);

// A-frags: partner half from global (issued first, flies under own MFMAs),
// own half from LDS parity buffer.
#define LOAD_HA(parR_)                                                         \
  h8 haP[4], haO[4];                                                           \
  {                                                                            \
    const _Float16* pb = hb_pa[parR_] + prd;                                   \
    _Pragma("unroll") for (int i = 0; i < 4; ++i)                              \
      haP[i] = *reinterpret_cast<const h8*>(pb + i * 32);                      \
    _Pragma("unroll") for (int i = 0; i < 4; ++i)                              \
      haO[i] = *reinterpret_cast<const h8*>(                                   \
          &smem[(parR_) * 4096 + lrd + (uint32_t)(i * 1024)]);                 \
  }

// z += h(t) @ rk : own slots first (LDS, ready), partner slots after
#define ZMM()                                                                  \
  _Pragma("unroll") for (int i = 0; i < 4; ++i)                                \
  _Pragma("unroll") for (int g = 0; g < 4; ++g)                                \
    acc[g] = __builtin_amdgcn_mfma_f32_16x16x32_f16(haO[i], Wreg[so + i][g],   \
                                                    acc[g], 0, 0, 0);          \
  _Pragma("unroll") for (int i = 0; i < 4; ++i)                                \
  _Pragma("unroll") for (int g = 0; g < 4; ++g)                                \
    acc[g] = __builtin_amdgcn_mfma_f32_16x16x32_f16(haP[i], Wreg[sp + i][g],   \
                                                    acc[g], 0, 0, 0);

// gates -> h stores (LDS parity + global partner copy) -> barrier -> flag
#define GATES_STORES(parW_, T_)                                                \
  {                                                                            \
    _Float16 hv[4];                                                            \
    _Pragma("unroll") for (int r = 0; r < 4; ++r) {                            \
      float iv = sigf(acc[0][r]);                                              \
      float fv = sigf(acc[1][r]);                                              \
      float gv = tanh_f(acc[2][r]);                                            \
      float ov = sigf(acc[3][r]);                                              \
      float cc = fv * cf[r] + iv * gv;                                         \
      cf[r] = cc;                                                              \
      hv[r] = (_Float16)(ov * tanh_f(cc));                                     \
    }                                                                          \
    _Float16* gw = hb_me[parW_] + quad * 512 + cloc;                           \
    _Pragma("unroll") for (int r = 0; r < 4; ++r) {                            \
      *reinterpret_cast<_Float16*>(                                            \
          &smem[(parW_) * 4096 + lwr + (uint32_t)(r * 16)]) = hv[r];           \
      gw[r * 128] = hv[r];                                                     \
    }                                                                          \
    __syncthreads(); /* drains vmcnt+lgkm per wave; all stores visible */      \
    if (tid == 0)                                                              \
      __hip_atomic_store(flagMe, (uint32_t)((T_) + 1), __ATOMIC_RELEASE,       \
                         __HIP_MEMORY_SCOPE_AGENT);                            \
  }

// 32 blocks x 512 threads: block = (tile = bid&15, half = bid>>4)
__global__ __launch_bounds__(512, 2)
void lstm_main_k(const float* __restrict__ pulse,      // (256,1024,8)
                 const float* __restrict__ embed,      // (1,2)
                 const float* __restrict__ b_mlp,      // (2)
                 const float* __restrict__ scale_w,    // (2)
                 const float* __restrict__ scale_b,    // (2)
                 const _Float16* __restrict__ rkT,
                 const _Float16* __restrict__ WeffT,
                 const _Float16* __restrict__ WmlpT,
                 const float* __restrict__ Deff,
                 const float* __restrict__ zbias,
                 const float* __restrict__ dbias,
                 _Float16* __restrict__ hbuf,
                 uint32_t* __restrict__ flags,
                 float* __restrict__ out)              // (256,35,2)
{
  __shared__ alignas(16) char smem[8192];   // own h-half, 2 parities x 4 KB

  const int tid  = threadIdx.x;
  const int w    = tid >> 6;
  const int lane = tid & 63;
  const int n    = lane & 15;
  const int quad = lane >> 4;
  const int bid  = blockIdx.x;
  const int tile = bid & 15;
  const int half = bid >> 4;
  const int b0   = tile * 16;
  const int hcol = half * 128 + w * 16 + n;   // my output col (per gate)

  // zero own-h LDS (both parities): 512 thr x 16 B = 8192 B
  {
    f4 zz; zz[0] = zz[1] = zz[2] = zz[3] = 0.f;
    *reinterpret_cast<f4*>(&smem[tid * 16]) = zz;
  }

  h8 z8;
#pragma unroll
  for (int j = 0; j < 8; ++j) z8[j] = (_Float16)0.f;

  // recurrent weights: ALL 8 K-slots x 4 gates register-resident (128 VGPR)
  const char* rkTb = reinterpret_cast<const char*>(rkT);
  const uint32_t gbo = (uint32_t)(hcol * 512 + quad * 16);
  h8 Wreg[8][4];
#pragma unroll
  for (int s = 0; s < 8; ++s)
#pragma unroll
    for (int g = 0; g < 4; ++g)
      Wreg[s][g] = *reinterpret_cast<const h8*>(
          rkTb + gbo + (uint32_t)(g * 131072 + s * 64));

  h8 Wf[4];
  float zb[4], db[4], D0v[4], D1v[4];
#pragma unroll
  for (int g = 0; g < 4; ++g) {
    int zc = g * 256 + hcol;
    Wf[g]  = (quad == 0) ? *reinterpret_cast<const h8*>(WeffT + (size_t)zc * 8) : z8;
    zb[g]  = zbias[zc];
    db[g]  = dbias[zc];
    D0v[g] = Deff[zc];
    D1v[g] = Deff[1024 + zc];
  }

  // per-lane addresses
  const uint32_t lrd  = (uint32_t)(quad * 256 + n * 16);       // own A-frag read
  const uint32_t cloc = (uint32_t)(w * 16 + n);                // local col
  const uint32_t lwr  = (uint32_t)((cloc >> 3) * 256 + quad * 64 + (cloc & 7) * 2);
  _Float16* hb_me[2];
  const _Float16* hb_pa[2];
#pragma unroll
  for (int p = 0; p < 2; ++p) {
    hb_me[p] = hbuf + ((size_t)(p * 16 + tile) * 2 + half) * 2048;
    hb_pa[p] = hbuf + ((size_t)(p * 16 + tile) * 2 + (1 - half)) * 2048;
  }
  const uint32_t prd = (uint32_t)(n * 128 + quad * 8);         // partner A-frag read
  uint32_t* flagMe = flags + (tile * 2 + half) * 16;
  uint32_t* flagPa = flags + (tile * 2 + (1 - half)) * 16;
  const int so = half * 4;       // own K-slot base (global slot idx)
  const int sp = 4 - so;         // partner K-slot base

  f4 cf; cf[0] = cf[1] = cf[2] = cf[3] = 0.f;
  const float* prow = pulse + (size_t)(b0 + n) * 8192;   // quad0 lanes use it

  __syncthreads();

  // ---------------- encoder: t = 0..1023 ----------------
#pragma unroll 1
  for (int t = 0; t < 1024; ++t) {
    const int parR = t & 1, parW = parR ^ 1;
    f4 px0, px1;
    px0[0]=px0[1]=px0[2]=px0[3]=0.f; px1[0]=px1[1]=px1[2]=px1[3]=0.f;
    if (quad == 0) {
      const f4* pp = reinterpret_cast<const f4*>(prow) + t * 2;
      px0 = pp[0]; px1 = pp[1];
    }
    POLL(t);
    LOAD_HA(parR);
    f4 acc[4];
#pragma unroll
    for (int g = 0; g < 4; ++g) {
      acc[g][0] = zb[g]; acc[g][1] = zb[g]; acc[g][2] = zb[g]; acc[g][3] = zb[g];
    }
    // x-affine (K padded 8->32, quad0 lanes carry data)
    h8 pa = z8;
    if (quad == 0) {
      pa[0] = (_Float16)px0[0]; pa[1] = (_Float16)px0[1];
      pa[2] = (_Float16)px0[2]; pa[3] = (_Float16)px0[3];
      pa[4] = (_Float16)px1[0]; pa[5] = (_Float16)px1[1];
      pa[6] = (_Float16)px1[2]; pa[7] = (_Float16)px1[3];
    }
#pragma unroll
    for (int g = 0; g < 4; ++g)
      acc[g] = __builtin_amdgcn_mfma_f32_16x16x32_f16(pa, Wf[g], acc[g], 0, 0, 0);
    ZMM();
    GATES_STORES(parW, t);
  }

  // ---------------- decoder: 35 steps ----------------
  const float swv = (n < 2) ? scale_w[n] : 0.f;
  const float sbv = (n < 2) ? scale_b[n] : 0.f;
  const float bmv = (n < 2) ? b_mlp[n]   : 0.f;
  const char* wmlpb = reinterpret_cast<const char*>(WmlpT);
  float tk0[4], tk1[4];
  {
    float e0 = embed[0], e1 = embed[1];
#pragma unroll
    for (int r = 0; r < 4; ++r) { tk0[r] = e0; tk1[r] = e1; }
  }

#pragma unroll 1
  for (int s = 0; s < 35; ++s) {
    const int T = 1024 + s;
    const int parR = T & 1, parW = parR ^ 1;
    POLL(T);
    LOAD_HA(parR);

    if (s > 0) {
      // pred_{s-1} = h(T) @ W_mlp + b_mlp (all waves; reuses ha frags)
      f4 pf; pf[0] = bmv; pf[1] = bmv; pf[2] = bmv; pf[3] = bmv;
      h8 wbv[8];
#pragma unroll
      for (int s2 = 0; s2 < 8; ++s2)
        wbv[s2] = (n < 2)
            ? *reinterpret_cast<const h8*>(
                  wmlpb + (uint32_t)(n * 512 + s2 * 64 + quad * 16))
            : z8;
#pragma unroll
      for (int i = 0; i < 4; ++i)
        pf = __builtin_amdgcn_mfma_f32_16x16x32_f16(haO[i], wbv[so + i], pf, 0, 0, 0);
#pragma unroll
      for (int i = 0; i < 4; ++i)
        pf = __builtin_amdgcn_mfma_f32_16x16x32_f16(haP[i], wbv[sp + i], pf, 0, 0, 0);
      if (half == 0 && w == 0 && n < 2) {
#pragma unroll
        for (int r = 0; r < 4; ++r)
          out[((size_t)(b0 + quad * 4 + r) * 35 + (s - 1)) * 2 + n] =
              pf[r] * swv + sbv;
      }
      // redistribute: lane needs tok[row=quad*4+r][e] from lane quad*16+e, reg r
#pragma unroll
      for (int r = 0; r < 4; ++r) {
        tk0[r] = __shfl(pf[r], quad * 16);
        tk1[r] = __shfl(pf[r], quad * 16 + 1);
      }
    }

    f4 acc[4];
#pragma unroll
    for (int g = 0; g < 4; ++g)
#pragma unroll
      for (int r = 0; r < 4; ++r)
        acc[g][r] = db[g] + tk0[r] * D0v[g] + tk1[r] * D1v[g];
    ZMM();
    GATES_STORES(parW, T);
  }

  // epilogue: pred_34 from h(1059) (half0 only writes out)
  if (half == 0) {
    POLL(1059);
    LOAD_HA(1);
    f4 pf; pf[0] = bmv; pf[1] = bmv; pf[2] = bmv; pf[3] = bmv;
    h8 wbv[8];
#pragma unroll
    for (int s2 = 0; s2 < 8; ++s2)
      wbv[s2] = (n < 2)
          ? *reinterpret_cast<const h8*>(
                wmlpb + (uint32_t)(n * 512 + s2 * 64 + quad * 16))
          : z8;
#pragma unroll
    for (int i = 0; i < 4; ++i)
      pf = __builtin_amdgcn_mfma_f32_16x16x32_f16(haO[i], wbv[so + i], pf, 0, 0, 0);
#pragma unroll
    for (int i = 0; i < 4; ++i)
      pf = __builtin_amdgcn_mfma_f32_16x16x32_f16(haP[i], wbv[sp + i], pf, 0, 0, 0);
    if (w == 0 && n < 2) {
#pragma unroll
      for (int r = 0; r < 4; ++r)
        out[((size_t)(b0 + quad * 4 + r) * 35 + 34) * 2 + n] = pf[r] * swv + sbv;
    }
  }
}

extern "C" void kernel_launch(void* const* d_in, const int* in_sizes, int n_in,
                              void* d_out, int out_size, void* d_ws, size_t ws_size,
                              hipStream_t stream) {
  const float* pulse    = (const float*)d_in[0];
  const float* bn_gamma = (const float*)d_in[1];
  const float* bn_beta  = (const float*)d_in[2];
  const float* bn_mean  = (const float*)d_in[3];
  const float* bn_var   = (const float*)d_in[4];
  const float* W_pulse  = (const float*)d_in[5];
  const float* b_pulse  = (const float*)d_in[6];
  const float* lstm_k   = (const float*)d_in[7];
  const float* lstm_rk  = (const float*)d_in[8];
  const float* lstm_b   = (const float*)d_in[9];
  const float* embed    = (const float*)d_in[10];
  const float* W_eis    = (const float*)d_in[11];
  const float* b_eis    = (const float*)d_in[12];
  const float* W_mlp    = (const float*)d_in[13];
  const float* b_mlp    = (const float*)d_in[14];
  const float* scale_w  = (const float*)d_in[15];
  const float* scale_b  = (const float*)d_in[16];

  char* ws = (char*)d_ws;
  uint32_t* flags  = (uint32_t*)(ws + WS_FLAGS);
  _Float16* hbuf   = (_Float16*)(ws + WS_HBUF);
  _Float16* rkT    = (_Float16*)(ws + WS_RKT);
  _Float16* WeffT  = (_Float16*)(ws + WS_WEFF);
  _Float16* WmlpT  = (_Float16*)(ws + WS_WMLP);
  float*    Deff   = (float*)(ws + WS_DEFF);
  float*    zbias  = (float*)(ws + WS_ZB);
  float*    dbias  = (float*)(ws + WS_DB);

  // zero flags + full h exchange buffer: (2048 + 262144)/4 = 66048 words
  zero_ws_k<<<258, 256, 0, stream>>>((uint32_t*)d_ws, 66048);
  precompute_k<<<1024, 256, 0, stream>>>(bn_gamma, bn_beta, bn_mean, bn_var,
                                         W_pulse, b_pulse, lstm_k, lstm_rk, lstm_b,
                                         W_eis, b_eis, W_mlp,
                                         rkT, WeffT, WmlpT, Deff, zbias, dbias);
  lstm_main_k<<<32, 512, 0, stream>>>(pulse, embed, b_mlp, scale_w, scale_b,
                                      rkT, WeffT, WmlpT, Deff, zbias, dbias,
                                      hbuf, flags, (float*)d_out);
}

// Round 6
// 4507.603 us; speedup vs baseline: 2.8021x; 2.8021x over previous
//
#include <hip/hip_runtime.h>
#include <cstdint>
#include <cstddef>

// ---------------------------------------------------------------------------
// Trainer_91216515433187: BN + Dense + LSTM encoder (1024 steps) + 35-step
// autoregressive LSTM decoder.
//
// Round 7: 32 WGs = 16 batch-tiles x 2 hidden-halves, recurrent weights truly
// register-resident this time:
//   * compile-time-indexed WO[4][4]/WP[4][4] (runtime 'half' only in the load
//     ADDRESS, never the array index — rule #20 was round 6's defect)
//   * asm("" : "+a"(frag)) pins: def becomes opaque asm output ->
//     non-rematerializable, homed in AGPRs (144 regs), MFMA reads AGPR B.
// Per step: x-affine + own-half MFMAs (LDS parity buffer, conflict-free b128)
// run BEFORE the partner poll; partner h-half read global->regs after a
// relaxed spin + one acquire. Gate biases/Deff in LDS (no remat-able scalar
// loads); pulse x prefetched one step ahead. ONE __syncthreads + release
// flag per step. Pairs (bid, bid+16) same-XCD under %8 (heuristic only).
// ---------------------------------------------------------------------------

typedef _Float16 h8 __attribute__((ext_vector_type(8)));
typedef float f4 __attribute__((ext_vector_type(4)));

// ws byte offsets
#define WS_FLAGS  0         // 16 tiles x 2 halves x 16 u32 = 2048
#define WS_HBUF   2048      // 2 par x 16 tiles x 2 halves x (16r x 128c) f16 = 262144
#define WS_RKT    264192    // 1024 cols x 256 k f16 = 524288
#define WS_WEFF   788480    // 1024 cols x 8 f f16 = 16384
#define WS_WMLP   804864    // 2 e x 256 k f16 = 1024
#define WS_DEFF   805888    // f32 [2][1024] = 8192
#define WS_ZB     814080    // 1024 f32
#define WS_DB     818176    // 1024 f32  -> end 822272

// LDS layout (16 KB)
#define LZB 8192            // zbias  [g4][cloc128] f32 = 2048
#define LDB 10240           // dbias
#define LD0 12288           // Deff0
#define LD1 14336           // Deff1
#define LDS_SZ 16384

__device__ __forceinline__ float fexp2(float x){
#if __has_builtin(__builtin_amdgcn_exp2f)
  return __builtin_amdgcn_exp2f(x);
#else
  return exp2f(x);
#endif
}
__device__ __forceinline__ float frcp(float x){
#if __has_builtin(__builtin_amdgcn_rcpf)
  return __builtin_amdgcn_rcpf(x);
#else
  return 1.f / x;
#endif
}
__device__ __forceinline__ float sigf(float x){
  return frcp(1.f + fexp2(-1.44269504f * x));
}
__device__ __forceinline__ float tanh_f(float x){
  return 2.f * frcp(1.f + fexp2(-2.88539008f * x)) - 1.f;
}

__global__ void zero_ws_k(uint32_t* __restrict__ p, int nw){
  int i = blockIdx.x * 256 + threadIdx.x;
  if (i < nw) p[i] = 0u;
}

// grid 1024 x 256 threads (known-correct)
__global__ void precompute_k(const float* __restrict__ bn_gamma,
                             const float* __restrict__ bn_beta,
                             const float* __restrict__ bn_mean,
                             const float* __restrict__ bn_var,
                             const float* __restrict__ W_pulse,   // (8,256)
                             const float* __restrict__ b_pulse,   // (256)
                             const float* __restrict__ lstm_k,    // (256,1024)
                             const float* __restrict__ lstm_rk,   // (256,1024)
                             const float* __restrict__ lstm_b,    // (1024)
                             const float* __restrict__ W_eis,     // (2,256)
                             const float* __restrict__ b_eis,     // (256)
                             const float* __restrict__ W_mlp,     // (256,2)
                             _Float16* __restrict__ rkT,          // [col][k]
                             _Float16* __restrict__ WeffT,        // [col][f]
                             _Float16* __restrict__ WmlpT,        // [e][k]
                             float* __restrict__ Deff,            // [e][col]
                             float* __restrict__ zbias,
                             float* __restrict__ dbias)
{
  int gid = blockIdx.x * 256 + threadIdx.x;   // 0..262143
  {
    int col = gid >> 8;
    int k   = gid & 255;
    rkT[col * 256 + k] = (_Float16)lstm_rk[k * 1024 + col];
  }
  if (gid < 512) {
    int e = gid >> 8, k = gid & 255;
    WmlpT[e * 256 + k] = (_Float16)W_mlp[k * 2 + e];
  }
  if (gid < 1024) {
    int j = gid;
    float a[8], bv[8];
#pragma unroll
    for (int f = 0; f < 8; ++f) {
      float af = bn_gamma[f] * rsqrtf(bn_var[f] + 1e-3f);
      a[f]  = af;
      bv[f] = bn_beta[f] - bn_mean[f] * af;
    }
    float m[8] = {0,0,0,0,0,0,0,0};
    float d0 = 0.f, d1 = 0.f, zb2 = 0.f, db2 = 0.f;
    for (int k = 0; k < 256; ++k) {
      float lk = lstm_k[k * 1024 + j];
#pragma unroll
      for (int f = 0; f < 8; ++f) m[f] += W_pulse[f * 256 + k] * lk;
      d0  += W_eis[k]       * lk;
      d1  += W_eis[256 + k] * lk;
      zb2 += b_pulse[k] * lk;
      db2 += b_eis[k]   * lk;
    }
    float zb = lstm_b[j] + zb2;
#pragma unroll
    for (int f = 0; f < 8; ++f) {
      zb += bv[f] * m[f];
      WeffT[j * 8 + f] = (_Float16)(a[f] * m[f]);
    }
    zbias[j] = zb;
    dbias[j] = lstm_b[j] + db2;
    Deff[j]        = d0;
    Deff[1024 + j] = d1;
  }
}

// relaxed spin, then one acquire load (single L1 invalidate)
#define POLL(wantT)                                                            \
  {                                                                            \
    while (__hip_atomic_load(flagPa, __ATOMIC_RELAXED,                         \
                             __HIP_MEMORY_SCOPE_AGENT) < (uint32_t)(wantT))    \
      __builtin_amdgcn_s_sleep(1);                                             \
    (void)__hip_atomic_load(flagPa, __ATOMIC_ACQUIRE,                          \
                            __HIP_MEMORY_SCOPE_AGENT);                         \
  }

#define LOAD_HAO(parR_)                                                        \
  h8 haO[4];                                                                   \
  _Pragma("unroll") for (int i = 0; i < 4; ++i)                                \
    haO[i] = *reinterpret_cast<const h8*>(                                     \
        &smem[(parR_) * 4096 + lrd + (uint32_t)(i * 1024)]);

#define LOAD_HAP(parR_)                                                        \
  h8 haP[4];                                                                   \
  {                                                                            \
    const _Float16* pb = hb_pa[parR_] + prd;                                   \
    _Pragma("unroll") for (int i = 0; i < 4; ++i)                              \
      haP[i] = *reinterpret_cast<const h8*>(pb + i * 32);                      \
  }

#define MM_OWN()                                                               \
  _Pragma("unroll") for (int i = 0; i < 4; ++i)                                \
  _Pragma("unroll") for (int g = 0; g < 4; ++g)                                \
    acc[g] = __builtin_amdgcn_mfma_f32_16x16x32_f16(haO[i], WO[i][g],          \
                                                    acc[g], 0, 0, 0);

#define MM_PAR()                                                               \
  _Pragma("unroll") for (int i = 0; i < 4; ++i)                                \
  _Pragma("unroll") for (int g = 0; g < 4; ++g)                                \
    acc[g] = __builtin_amdgcn_mfma_f32_16x16x32_f16(haP[i], WP[i][g],          \
                                                    acc[g], 0, 0, 0);

// gates -> h stores (LDS parity + global partner copy) -> barrier -> flag
#define GATES_STORES(parW_, T_)                                                \
  {                                                                            \
    _Float16 hv[4];                                                            \
    _Pragma("unroll") for (int r = 0; r < 4; ++r) {                            \
      float iv = sigf(acc[0][r]);                                              \
      float fv = sigf(acc[1][r]);                                              \
      float gv = tanh_f(acc[2][r]);                                            \
      float ov = sigf(acc[3][r]);                                              \
      float cc = fv * cf[r] + iv * gv;                                         \
      cf[r] = cc;                                                              \
      hv[r] = (_Float16)(ov * tanh_f(cc));                                     \
    }                                                                          \
    _Float16* gw = hb_me[parW_] + quad * 512 + cloc;                           \
    _Pragma("unroll") for (int r = 0; r < 4; ++r) {                            \
      *reinterpret_cast<_Float16*>(                                            \
          &smem[(parW_) * 4096 + lwr + (uint32_t)(r * 16)]) = hv[r];           \
      gw[r * 128] = hv[r];                                                     \
    }                                                                          \
    __syncthreads(); /* per-wave vmcnt+lgkm drained; all stores in L2 */       \
    if (tid == 0)                                                              \
      __hip_atomic_store(flagMe, (uint32_t)((T_) + 1), __ATOMIC_RELEASE,       \
                         __HIP_MEMORY_SCOPE_AGENT);                            \
  }

// 32 blocks x 512 threads: block = (tile = bid&15, half = bid>>4)
__global__ __launch_bounds__(512, 2)
void lstm_main_k(const float* __restrict__ pulse,      // (256,1024,8)
                 const float* __restrict__ embed,      // (1,2)
                 const float* __restrict__ b_mlp,      // (2)
                 const float* __restrict__ scale_w,    // (2)
                 const float* __restrict__ scale_b,    // (2)
                 const _Float16* __restrict__ rkT,
                 const _Float16* __restrict__ WeffT,
                 const _Float16* __restrict__ WmlpT,
                 const float* __restrict__ Deff,
                 const float* __restrict__ zbias,
                 const float* __restrict__ dbias,
                 _Float16* __restrict__ hbuf,
                 uint32_t* __restrict__ flags,
                 float* __restrict__ out)              // (256,35,2)
{
  __shared__ alignas(16) char smem[LDS_SZ];

  const int tid  = threadIdx.x;
  const int w    = tid >> 6;
  const int lane = tid & 63;
  const int n    = lane & 15;
  const int quad = lane >> 4;
  const int bid  = blockIdx.x;
  const int tile = bid & 15;
  const int half = bid >> 4;
  const int b0   = tile * 16;
  const int cloc = w * 16 + n;                // local hidden col 0..127
  const int hcol = half * 128 + cloc;         // global hidden col

  // zero own-h LDS (both parities, 8 KB)
  {
    f4 zz; zz[0] = zz[1] = zz[2] = zz[3] = 0.f;
    *reinterpret_cast<f4*>(&smem[tid * 16]) = zz;
  }
  // biases/Deff -> LDS (quad0 lanes cover all cloc)
  if (quad == 0) {
#pragma unroll
    for (int g = 0; g < 4; ++g) {
      int zc = g * 256 + hcol;
      *reinterpret_cast<float*>(&smem[LZB + g * 512 + cloc * 4]) = zbias[zc];
      *reinterpret_cast<float*>(&smem[LDB + g * 512 + cloc * 4]) = dbias[zc];
      *reinterpret_cast<float*>(&smem[LD0 + g * 512 + cloc * 4]) = Deff[zc];
      *reinterpret_cast<float*>(&smem[LD1 + g * 512 + cloc * 4]) = Deff[1024 + zc];
    }
  }

  h8 z8;
#pragma unroll
  for (int j = 0; j < 8; ++j) z8[j] = (_Float16)0.f;

  // ---- recurrent weights: register-resident, AGPR-pinned ----
  const char* rkTb = reinterpret_cast<const char*>(rkT);
  const uint32_t gbo = (uint32_t)(hcol * 512 + quad * 16);
  const uint32_t sbO = (uint32_t)(half * 256);   // own slot byte base (so*64)
  const uint32_t sbP = 256u - sbO;               // partner slot byte base
  h8 WO[4][4], WP[4][4];
#pragma unroll
  for (int i = 0; i < 4; ++i)
#pragma unroll
    for (int g = 0; g < 4; ++g) {
      WO[i][g] = *reinterpret_cast<const h8*>(
          rkTb + gbo + (uint32_t)(g * 131072) + sbO + (uint32_t)(i * 64));
      asm("" : "+a"(WO[i][g]));
      WP[i][g] = *reinterpret_cast<const h8*>(
          rkTb + gbo + (uint32_t)(g * 131072) + sbP + (uint32_t)(i * 64));
      asm("" : "+a"(WP[i][g]));
    }
  h8 Wf[4];
#pragma unroll
  for (int g = 0; g < 4; ++g) {
    Wf[g] = (quad == 0)
        ? *reinterpret_cast<const h8*>(WeffT + (size_t)(g * 256 + hcol) * 8)
        : z8;
    asm("" : "+a"(Wf[g]));
  }

  // per-lane addresses
  const uint32_t lrd = (uint32_t)(quad * 256 + n * 16);   // own A-frag read
  const uint32_t lwr = (uint32_t)((cloc >> 3) * 256 + quad * 64 + (cloc & 7) * 2);
  _Float16* hb_me[2];
  const _Float16* hb_pa[2];
#pragma unroll
  for (int p = 0; p < 2; ++p) {
    hb_me[p] = hbuf + ((size_t)(p * 16 + tile) * 2 + half) * 2048;
    hb_pa[p] = hbuf + ((size_t)(p * 16 + tile) * 2 + (1 - half)) * 2048;
  }
  const uint32_t prd = (uint32_t)(n * 128 + quad * 8);    // partner A-frag read
  uint32_t* flagMe = flags + (tile * 2 + half) * 16;
  uint32_t* flagPa = flags + (tile * 2 + (1 - half)) * 16;

  f4 cf; cf[0] = cf[1] = cf[2] = cf[3] = 0.f;
  const float* prow = pulse + (size_t)(b0 + n) * 8192;    // quad0 lanes

  // prologue: x(0) prefetch
  f4 px0, px1;
  px0[0]=px0[1]=px0[2]=px0[3]=0.f; px1[0]=px1[1]=px1[2]=px1[3]=0.f;
  if (quad == 0) {
    const f4* pp = reinterpret_cast<const f4*>(prow);
    px0 = pp[0]; px1 = pp[1];
  }

  __syncthreads();

  // ---------------- encoder: t = 0..1023 ----------------
#pragma unroll 1
  for (int t = 0; t < 1024; ++t) {
    const int parR = t & 1, parW = parR ^ 1;

    // acc init from zbias (LDS, quad-broadcast)
    f4 acc[4];
#pragma unroll
    for (int g = 0; g < 4; ++g) {
      float zv = *reinterpret_cast<const float*>(
          &smem[LZB + (uint32_t)(g * 512 + cloc * 4)]);
      acc[g][0] = zv; acc[g][1] = zv; acc[g][2] = zv; acc[g][3] = zv;
    }
    // x-affine (prefetched px; K padded 8->32, quad0 lanes carry data)
    h8 pa = z8;
    if (quad == 0) {
      pa[0] = (_Float16)px0[0]; pa[1] = (_Float16)px0[1];
      pa[2] = (_Float16)px0[2]; pa[3] = (_Float16)px0[3];
      pa[4] = (_Float16)px1[0]; pa[5] = (_Float16)px1[1];
      pa[6] = (_Float16)px1[2]; pa[7] = (_Float16)px1[3];
    }
#pragma unroll
    for (int g = 0; g < 4; ++g)
      acc[g] = __builtin_amdgcn_mfma_f32_16x16x32_f16(pa, Wf[g], acc[g], 0, 0, 0);

    // own half (LDS, ready) — before the poll
    LOAD_HAO(parR);
    MM_OWN();

    // x(t+1) prefetch (full-step flight window)
    if (quad == 0) {
      int tp = (t + 1 < 1024) ? t + 1 : 1023;
      const f4* pp = reinterpret_cast<const f4*>(prow) + tp * 2;
      px0 = pp[0]; px1 = pp[1];
    }

    // partner half
    POLL(t);
    LOAD_HAP(parR);
    MM_PAR();

    GATES_STORES(parW, t);
  }

  // ---------------- decoder: 35 steps ----------------
  const float swv = (n < 2) ? scale_w[n] : 0.f;
  const float sbv = (n < 2) ? scale_b[n] : 0.f;
  const float bmv = (n < 2) ? b_mlp[n]   : 0.f;
  const char* wmlpb = reinterpret_cast<const char*>(WmlpT);
  float tk0[4], tk1[4];
  {
    float e0 = embed[0], e1 = embed[1];
#pragma unroll
    for (int r = 0; r < 4; ++r) { tk0[r] = e0; tk1[r] = e1; }
  }

#pragma unroll 1
  for (int s = 0; s < 35; ++s) {
    const int T = 1024 + s;
    const int parR = T & 1, parW = parR ^ 1;
    POLL(T);
    LOAD_HAO(parR);
    LOAD_HAP(parR);

    if (s > 0) {
      // pred_{s-1} = h(T) @ W_mlp + b_mlp (all waves; reuses ha frags)
      f4 pf; pf[0] = bmv; pf[1] = bmv; pf[2] = bmv; pf[3] = bmv;
#pragma unroll
      for (int i = 0; i < 4; ++i) {
        h8 wb = (n < 2)
            ? *reinterpret_cast<const h8*>(
                  wmlpb + (uint32_t)(n * 512 + quad * 16) + sbO + (uint32_t)(i * 64))
            : z8;
        pf = __builtin_amdgcn_mfma_f32_16x16x32_f16(haO[i], wb, pf, 0, 0, 0);
      }
#pragma unroll
      for (int i = 0; i < 4; ++i) {
        h8 wb = (n < 2)
            ? *reinterpret_cast<const h8*>(
                  wmlpb + (uint32_t)(n * 512 + quad * 16) + sbP + (uint32_t)(i * 64))
            : z8;
        pf = __builtin_amdgcn_mfma_f32_16x16x32_f16(haP[i], wb, pf, 0, 0, 0);
      }
      if (half == 0 && w == 0 && n < 2) {
#pragma unroll
        for (int r = 0; r < 4; ++r)
          out[((size_t)(b0 + quad * 4 + r) * 35 + (s - 1)) * 2 + n] =
              pf[r] * swv + sbv;
      }
      // lane (n,quad) needs tok[row=quad*4+r][e] from lane quad*16+e, reg r
#pragma unroll
      for (int r = 0; r < 4; ++r) {
        tk0[r] = __shfl(pf[r], quad * 16);
        tk1[r] = __shfl(pf[r], quad * 16 + 1);
      }
    }

    f4 acc[4];
#pragma unroll
    for (int g = 0; g < 4; ++g) {
      float dbv = *reinterpret_cast<const float*>(
          &smem[LDB + (uint32_t)(g * 512 + cloc * 4)]);
      float d0v = *reinterpret_cast<const float*>(
          &smem[LD0 + (uint32_t)(g * 512 + cloc * 4)]);
      float d1v = *reinterpret_cast<const float*>(
          &smem[LD1 + (uint32_t)(g * 512 + cloc * 4)]);
#pragma unroll
      for (int r = 0; r < 4; ++r)
        acc[g][r] = dbv + tk0[r] * d0v + tk1[r] * d1v;
    }
    MM_OWN();
    MM_PAR();

    GATES_STORES(parW, T);
  }

  // epilogue: pred_34 from h(1059) (half0 writes out)
  if (half == 0) {
    POLL(1059);
    LOAD_HAO(1);
    LOAD_HAP(1);
    f4 pf; pf[0] = bmv; pf[1] = bmv; pf[2] = bmv; pf[3] = bmv;
#pragma unroll
    for (int i = 0; i < 4; ++i) {
      h8 wb = (n < 2)
          ? *reinterpret_cast<const h8*>(
                wmlpb + (uint32_t)(n * 512 + quad * 16) + sbO + (uint32_t)(i * 64))
          : z8;
      pf = __builtin_amdgcn_mfma_f32_16x16x32_f16(haO[i], wb, pf, 0, 0, 0);
    }
#pragma unroll
    for (int i = 0; i < 4; ++i) {
      h8 wb = (n < 2)
          ? *reinterpret_cast<const h8*>(
                wmlpb + (uint32_t)(n * 512 + quad * 16) + sbP + (uint32_t)(i * 64))
          : z8;
      pf = __builtin_amdgcn_mfma_f32_16x16x32_f16(haP[i], wb, pf, 0, 0, 0);
    }
    if (w == 0 && n < 2) {
#pragma unroll
      for (int r = 0; r < 4; ++r)
        out[((size_t)(b0 + quad * 4 + r) * 35 + 34) * 2 + n] = pf[r] * swv + sbv;
    }
  }
}

extern "C" void kernel_launch(void* const* d_in, const int* in_sizes, int n_in,
                              void* d_out, int out_size, void* d_ws, size_t ws_size,
                              hipStream_t stream) {
  const float* pulse    = (const float*)d_in[0];
  const float* bn_gamma = (const float*)d_in[1];
  const float* bn_beta  = (const float*)d_in[2];
  const float* bn_mean  = (const float*)d_in[3];
  const float* bn_var   = (const float*)d_in[4];
  const float* W_pulse  = (const float*)d_in[5];
  const float* b_pulse  = (const float*)d_in[6];
  const float* lstm_k   = (const float*)d_in[7];
  const float* lstm_rk  = (const float*)d_in[8];
  const float* lstm_b   = (const float*)d_in[9];
  const float* embed    = (const float*)d_in[10];
  const float* W_eis    = (const float*)d_in[11];
  const float* b_eis    = (const float*)d_in[12];
  const float* W_mlp    = (const float*)d_in[13];
  const float* b_mlp    = (const float*)d_in[14];
  const float* scale_w  = (const float*)d_in[15];
  const float* scale_b  = (const float*)d_in[16];

  char* ws = (char*)d_ws;
  uint32_t* flags  = (uint32_t*)(ws + WS_FLAGS);
  _Float16* hbuf   = (_Float16*)(ws + WS_HBUF);
  _Float16* rkT    = (_Float16*)(ws + WS_RKT);
  _Float16* WeffT  = (_Float16*)(ws + WS_WEFF);
  _Float16* WmlpT  = (_Float16*)(ws + WS_WMLP);
  float*    Deff   = (float*)(ws + WS_DEFF);
  float*    zbias  = (float*)(ws + WS_ZB);
  float*    dbias  = (float*)(ws + WS_DB);

  // zero flags + h exchange buffer: (2048 + 262144)/4 = 66048 words
  zero_ws_k<<<258, 256, 0, stream>>>((uint32_t*)d_ws, 66048);
  precompute_k<<<1024, 256, 0, stream>>>(bn_gamma, bn_beta, bn_mean, bn_var,
                                         W_pulse, b_pulse, lstm_k, lstm_rk, lstm_b,
                                         W_eis, b_eis, W_mlp,
                                         rkT, WeffT, WmlpT, Deff, zbias, dbias);
  lstm_main_k<<<32, 512, 0, stream>>>(pulse, embed, b_mlp, scale_w, scale_b,
                                      rkT, WeffT, WmlpT, Deff, zbias, dbias,
                                      hbuf, flags, (float*)d_out);
}

// Round 7
// 3674.207 us; speedup vs baseline: 3.4377x; 1.2268x over previous
//
#include <hip/hip_runtime.h>
#include <cstdint>
#include <cstddef>

// ---------------------------------------------------------------------------
// Trainer_91216515433187: BN + Dense + LSTM encoder (1024 steps) + 35-step
// autoregressive LSTM decoder.
//
// Round 8: R7's topology (32 WGs = 16 tiles x 2 hidden-halves, recurrent
// weights fully register/AGPR-resident, own h-half in LDS) with a FENCE-FREE
// exchange. R7's floor (~4.2us/step) was agent-scope acquire/release:
// on gfx950 acquire = buffer_inv sc1 (L2 invalidate), release = buffer_wbl2
// (L2 writeback) — per-XCD L2 non-coherence makes them full cache-maintenance
// ops, several thousand cycles per step. This round uses RELAXED scoped
// atomics only (compile to sc0 sc1 cache-bypassing accesses serviced at the
// Infinity Cache coherent point — no wbl2/inv):
//   * h data: 2 rows packed per u32, 2 relaxed-agent u32 stores/thread;
//     partner reads u64 relaxed-agent loads + v_perm_b32 row extraction.
//   * ordering: __syncthreads() drains each wave's vmcnt (sc1 stores are
//     then globally visible) -> tid0 relaxed flag store; partner spins on
//     relaxed loads (no inv) + compiler barrier.
// Everything else identical to R7 (pinned weights, LDS biases, x prefetch,
// decoder pred via reused A-frags + __shfl token redistribution).
// ---------------------------------------------------------------------------

typedef _Float16 h8 __attribute__((ext_vector_type(8)));
typedef float f4 __attribute__((ext_vector_type(4)));

// ws byte offsets
#define WS_FLAGS  0         // 16 tiles x 2 halves x 16 u32 = 2048
#define WS_HBUF   2048      // 2 par x 16 tiles x 2 halves x 1024 u32 = 262144
#define WS_RKT    264192    // 1024 cols x 256 k f16 = 524288
#define WS_WEFF   788480    // 1024 cols x 8 f f16 = 16384
#define WS_WMLP   804864    // 2 e x 256 k f16 = 1024
#define WS_DEFF   805888    // f32 [2][1024] = 8192
#define WS_ZB     814080    // 1024 f32
#define WS_DB     818176    // 1024 f32  -> end 822272

// LDS layout (16 KB)
#define LZB 8192            // zbias  [g4][cloc128] f32 = 2048
#define LDB 10240           // dbias
#define LD0 12288           // Deff0
#define LD1 14336           // Deff1
#define LDS_SZ 16384

__device__ __forceinline__ float fexp2(float x){
#if __has_builtin(__builtin_amdgcn_exp2f)
  return __builtin_amdgcn_exp2f(x);
#else
  return exp2f(x);
#endif
}
__device__ __forceinline__ float frcp(float x){
#if __has_builtin(__builtin_amdgcn_rcpf)
  return __builtin_amdgcn_rcpf(x);
#else
  return 1.f / x;
#endif
}
__device__ __forceinline__ float sigf(float x){
  return frcp(1.f + fexp2(-1.44269504f * x));
}
__device__ __forceinline__ float tanh_f(float x){
  return 2.f * frcp(1.f + fexp2(-2.88539008f * x)) - 1.f;
}
__device__ __forceinline__ uint32_t pack16(_Float16 a, _Float16 b){
  union { _Float16 h[2]; uint32_t u; } t;
  t.h[0] = a; t.h[1] = b;
  return t.u;
}

__global__ void zero_ws_k(uint32_t* __restrict__ p, int nw){
  int i = blockIdx.x * 256 + threadIdx.x;
  if (i < nw) p[i] = 0u;
}

// grid 1024 x 256 threads (known-correct)
__global__ void precompute_k(const float* __restrict__ bn_gamma,
                             const float* __restrict__ bn_beta,
                             const float* __restrict__ bn_mean,
                             const float* __restrict__ bn_var,
                             const float* __restrict__ W_pulse,   // (8,256)
                             const float* __restrict__ b_pulse,   // (256)
                             const float* __restrict__ lstm_k,    // (256,1024)
                             const float* __restrict__ lstm_rk,   // (256,1024)
                             const float* __restrict__ lstm_b,    // (1024)
                             const float* __restrict__ W_eis,     // (2,256)
                             const float* __restrict__ b_eis,     // (256)
                             const float* __restrict__ W_mlp,     // (256,2)
                             _Float16* __restrict__ rkT,          // [col][k]
                             _Float16* __restrict__ WeffT,        // [col][f]
                             _Float16* __restrict__ WmlpT,        // [e][k]
                             float* __restrict__ Deff,            // [e][col]
                             float* __restrict__ zbias,
                             float* __restrict__ dbias)
{
  int gid = blockIdx.x * 256 + threadIdx.x;   // 0..262143
  {
    int col = gid >> 8;
    int k   = gid & 255;
    rkT[col * 256 + k] = (_Float16)lstm_rk[k * 1024 + col];
  }
  if (gid < 512) {
    int e = gid >> 8, k = gid & 255;
    WmlpT[e * 256 + k] = (_Float16)W_mlp[k * 2 + e];
  }
  if (gid < 1024) {
    int j = gid;
    float a[8], bv[8];
#pragma unroll
    for (int f = 0; f < 8; ++f) {
      float af = bn_gamma[f] * rsqrtf(bn_var[f] + 1e-3f);
      a[f]  = af;
      bv[f] = bn_beta[f] - bn_mean[f] * af;
    }
    float m[8] = {0,0,0,0,0,0,0,0};
    float d0 = 0.f, d1 = 0.f, zb2 = 0.f, db2 = 0.f;
    for (int k = 0; k < 256; ++k) {
      float lk = lstm_k[k * 1024 + j];
#pragma unroll
      for (int f = 0; f < 8; ++f) m[f] += W_pulse[f * 256 + k] * lk;
      d0  += W_eis[k]       * lk;
      d1  += W_eis[256 + k] * lk;
      zb2 += b_pulse[k] * lk;
      db2 += b_eis[k]   * lk;
    }
    float zb = lstm_b[j] + zb2;
#pragma unroll
    for (int f = 0; f < 8; ++f) {
      zb += bv[f] * m[f];
      WeffT[j * 8 + f] = (_Float16)(a[f] * m[f]);
    }
    zbias[j] = zb;
    dbias[j] = lstm_b[j] + db2;
    Deff[j]        = d0;
    Deff[1024 + j] = d1;
  }
}

// relaxed spin (sc0sc1 load, NO buffer_inv); compiler barrier after
#define POLL(wantT)                                                            \
  {                                                                            \
    while (__hip_atomic_load(flagPa, __ATOMIC_RELAXED,                         \
                             __HIP_MEMORY_SCOPE_AGENT) < (uint32_t)(wantT))    \
      __builtin_amdgcn_s_sleep(1);                                             \
    asm volatile("" ::: "memory");                                             \
  }

#define LOAD_HAO(parR_)                                                        \
  h8 haO[4];                                                                   \
  _Pragma("unroll") for (int i = 0; i < 4; ++i)                                \
    haO[i] = *reinterpret_cast<const h8*>(                                     \
        &smem[(parR_) * 4096 + lrd + (uint32_t)(i * 1024)]);

// partner frags: u64 relaxed-agent loads (32B/frag) + v_perm row extraction
#define LOAD_HAP(parR_)                                                        \
  h8 haP[4];                                                                   \
  {                                                                            \
    const uint64_t* pb =                                                       \
        reinterpret_cast<const uint64_t*>(hb_pa[parR_]) + prd64;               \
    _Pragma("unroll") for (int i = 0; i < 4; ++i) {                            \
      uint64_t t0 = __hip_atomic_load(pb + i * 16 + 0, __ATOMIC_RELAXED,       \
                                      __HIP_MEMORY_SCOPE_AGENT);               \
      uint64_t t1 = __hip_atomic_load(pb + i * 16 + 1, __ATOMIC_RELAXED,       \
                                      __HIP_MEMORY_SCOPE_AGENT);               \
      uint64_t t2 = __hip_atomic_load(pb + i * 16 + 2, __ATOMIC_RELAXED,       \
                                      __HIP_MEMORY_SCOPE_AGENT);               \
      uint64_t t3 = __hip_atomic_load(pb + i * 16 + 3, __ATOMIC_RELAXED,       \
                                      __HIP_MEMORY_SCOPE_AGENT);               \
      union { uint32_t u[4]; h8 v; } q;                                        \
      q.u[0] = __builtin_amdgcn_perm((uint32_t)(t0 >> 32), (uint32_t)t0, psel);\
      q.u[1] = __builtin_amdgcn_perm((uint32_t)(t1 >> 32), (uint32_t)t1, psel);\
      q.u[2] = __builtin_amdgcn_perm((uint32_t)(t2 >> 32), (uint32_t)t2, psel);\
      q.u[3] = __builtin_amdgcn_perm((uint32_t)(t3 >> 32), (uint32_t)t3, psel);\
      haP[i] = q.v;                                                            \
    }                                                                          \
  }

#define MM_OWN()                                                               \
  _Pragma("unroll") for (int i = 0; i < 4; ++i)                                \
  _Pragma("unroll") for (int g = 0; g < 4; ++g)                                \
    acc[g] = __builtin_amdgcn_mfma_f32_16x16x32_f16(haO[i], WO[i][g],          \
                                                    acc[g], 0, 0, 0);

#define MM_PAR()                                                               \
  _Pragma("unroll") for (int i = 0; i < 4; ++i)                                \
  _Pragma("unroll") for (int g = 0; g < 4; ++g)                                \
    acc[g] = __builtin_amdgcn_mfma_f32_16x16x32_f16(haP[i], WP[i][g],          \
                                                    acc[g], 0, 0, 0);

// gates -> h stores (LDS parity + packed relaxed-agent u32 global stores)
// -> __syncthreads (vmcnt drain = sc1 stores globally visible) -> relaxed flag
#define GATES_STORES(parW_, T_)                                                \
  {                                                                            \
    _Float16 hv[4];                                                            \
    _Pragma("unroll") for (int r = 0; r < 4; ++r) {                            \
      float iv = sigf(acc[0][r]);                                              \
      float fv = sigf(acc[1][r]);                                              \
      float gv = tanh_f(acc[2][r]);                                            \
      float ov = sigf(acc[3][r]);                                              \
      float cc = fv * cf[r] + iv * gv;                                         \
      cf[r] = cc;                                                              \
      hv[r] = (_Float16)(ov * tanh_f(cc));                                     \
    }                                                                          \
    uint32_t* gw = hb_me[parW_] + (uint32_t)(quad * 256 + cloc);               \
    __hip_atomic_store(gw, pack16(hv[0], hv[1]), __ATOMIC_RELAXED,             \
                       __HIP_MEMORY_SCOPE_AGENT);                              \
    __hip_atomic_store(gw + 128, pack16(hv[2], hv[3]), __ATOMIC_RELAXED,       \
                       __HIP_MEMORY_SCOPE_AGENT);                              \
    _Pragma("unroll") for (int r = 0; r < 4; ++r)                              \
      *reinterpret_cast<_Float16*>(                                            \
          &smem[(parW_) * 4096 + lwr + (uint32_t)(r * 16)]) = hv[r];           \
    __syncthreads(); /* per-wave vmcnt drained: sc1 stores visible at IF */    \
    if (tid == 0)                                                              \
      __hip_atomic_store(flagMe, (uint32_t)((T_) + 1), __ATOMIC_RELAXED,       \
                         __HIP_MEMORY_SCOPE_AGENT);                            \
  }

// 32 blocks x 512 threads: block = (tile = bid&15, half = bid>>4)
__global__ __launch_bounds__(512, 2)
void lstm_main_k(const float* __restrict__ pulse,      // (256,1024,8)
                 const float* __restrict__ embed,      // (1,2)
                 const float* __restrict__ b_mlp,      // (2)
                 const float* __restrict__ scale_w,    // (2)
                 const float* __restrict__ scale_b,    // (2)
                 const _Float16* __restrict__ rkT,
                 const _Float16* __restrict__ WeffT,
                 const _Float16* __restrict__ WmlpT,
                 const float* __restrict__ Deff,
                 const float* __restrict__ zbias,
                 const float* __restrict__ dbias,
                 uint32_t* __restrict__ hbuf,
                 uint32_t* __restrict__ flags,
                 float* __restrict__ out)              // (256,35,2)
{
  __shared__ alignas(16) char smem[LDS_SZ];

  const int tid  = threadIdx.x;
  const int w    = tid >> 6;
  const int lane = tid & 63;
  const int n    = lane & 15;
  const int quad = lane >> 4;
  const int bid  = blockIdx.x;
  const int tile = bid & 15;
  const int half = bid >> 4;
  const int b0   = tile * 16;
  const int cloc = w * 16 + n;                // local hidden col 0..127
  const int hcol = half * 128 + cloc;         // global hidden col

  // zero own-h LDS (both parities, 8 KB)
  {
    f4 zz; zz[0] = zz[1] = zz[2] = zz[3] = 0.f;
    *reinterpret_cast<f4*>(&smem[tid * 16]) = zz;
  }
  // biases/Deff -> LDS (quad0 lanes cover all cloc)
  if (quad == 0) {
#pragma unroll
    for (int g = 0; g < 4; ++g) {
      int zc = g * 256 + hcol;
      *reinterpret_cast<float*>(&smem[LZB + g * 512 + cloc * 4]) = zbias[zc];
      *reinterpret_cast<float*>(&smem[LDB + g * 512 + cloc * 4]) = dbias[zc];
      *reinterpret_cast<float*>(&smem[LD0 + g * 512 + cloc * 4]) = Deff[zc];
      *reinterpret_cast<float*>(&smem[LD1 + g * 512 + cloc * 4]) = Deff[1024 + zc];
    }
  }

  h8 z8;
#pragma unroll
  for (int j = 0; j < 8; ++j) z8[j] = (_Float16)0.f;

  // ---- recurrent weights: register-resident, AGPR-pinned ----
  const char* rkTb = reinterpret_cast<const char*>(rkT);
  const uint32_t gbo = (uint32_t)(hcol * 512 + quad * 16);
  const uint32_t sbO = (uint32_t)(half * 256);   // own slot byte base
  const uint32_t sbP = 256u - sbO;               // partner slot byte base
  h8 WO[4][4], WP[4][4];
#pragma unroll
  for (int i = 0; i < 4; ++i)
#pragma unroll
    for (int g = 0; g < 4; ++g) {
      WO[i][g] = *reinterpret_cast<const h8*>(
          rkTb + gbo + (uint32_t)(g * 131072) + sbO + (uint32_t)(i * 64));
      asm("" : "+a"(WO[i][g]));
      WP[i][g] = *reinterpret_cast<const h8*>(
          rkTb + gbo + (uint32_t)(g * 131072) + sbP + (uint32_t)(i * 64));
      asm("" : "+a"(WP[i][g]));
    }
  h8 Wf[4];
#pragma unroll
  for (int g = 0; g < 4; ++g) {
    Wf[g] = (quad == 0)
        ? *reinterpret_cast<const h8*>(WeffT + (size_t)(g * 256 + hcol) * 8)
        : z8;
    asm("" : "+a"(Wf[g]));
  }

  // per-lane addresses
  const uint32_t lrd = (uint32_t)(quad * 256 + n * 16);   // own A-frag read
  const uint32_t lwr = (uint32_t)((cloc >> 3) * 256 + quad * 64 + (cloc & 7) * 2);
  uint32_t* hb_me[2];
  const uint32_t* hb_pa[2];
#pragma unroll
  for (int p = 0; p < 2; ++p) {
    hb_me[p] = hbuf + ((size_t)(p * 16 + tile) * 2 + half) * 1024;
    hb_pa[p] = hbuf + ((size_t)(p * 16 + tile) * 2 + (1 - half)) * 1024;
  }
  const uint32_t prd64 = (uint32_t)((n >> 1) * 64 + quad * 4);  // u64 idx
  const uint32_t psel  = (n & 1) ? 0x07060302u : 0x05040100u;
  uint32_t* flagMe = flags + (tile * 2 + half) * 16;
  uint32_t* flagPa = flags + (tile * 2 + (1 - half)) * 16;

  f4 cf; cf[0] = cf[1] = cf[2] = cf[3] = 0.f;
  const float* prow = pulse + (size_t)(b0 + n) * 8192;    // quad0 lanes

  // prologue: x(0) prefetch
  f4 px0, px1;
  px0[0]=px0[1]=px0[2]=px0[3]=0.f; px1[0]=px1[1]=px1[2]=px1[3]=0.f;
  if (quad == 0) {
    const f4* pp = reinterpret_cast<const f4*>(prow);
    px0 = pp[0]; px1 = pp[1];
  }

  __syncthreads();

  // ---------------- encoder: t = 0..1023 ----------------
#pragma unroll 1
  for (int t = 0; t < 1024; ++t) {
    const int parR = t & 1, parW = parR ^ 1;

    // acc init from zbias (LDS, quad-broadcast)
    f4 acc[4];
#pragma unroll
    for (int g = 0; g < 4; ++g) {
      float zv = *reinterpret_cast<const float*>(
          &smem[LZB + (uint32_t)(g * 512 + cloc * 4)]);
      acc[g][0] = zv; acc[g][1] = zv; acc[g][2] = zv; acc[g][3] = zv;
    }
    // x-affine (prefetched px; K padded 8->32, quad0 lanes carry data)
    h8 pa = z8;
    if (quad == 0) {
      pa[0] = (_Float16)px0[0]; pa[1] = (_Float16)px0[1];
      pa[2] = (_Float16)px0[2]; pa[3] = (_Float16)px0[3];
      pa[4] = (_Float16)px1[0]; pa[5] = (_Float16)px1[1];
      pa[6] = (_Float16)px1[2]; pa[7] = (_Float16)px1[3];
    }
#pragma unroll
    for (int g = 0; g < 4; ++g)
      acc[g] = __builtin_amdgcn_mfma_f32_16x16x32_f16(pa, Wf[g], acc[g], 0, 0, 0);

    // own half (LDS, ready) — before the poll
    LOAD_HAO(parR);
    MM_OWN();

    // x(t+1) prefetch (full-step flight window)
    if (quad == 0) {
      int tp = (t + 1 < 1024) ? t + 1 : 1023;
      const f4* pp = reinterpret_cast<const f4*>(prow) + tp * 2;
      px0 = pp[0]; px1 = pp[1];
    }

    // partner half
    POLL(t);
    LOAD_HAP(parR);
    MM_PAR();

    GATES_STORES(parW, t);
  }

  // ---------------- decoder: 35 steps ----------------
  const float swv = (n < 2) ? scale_w[n] : 0.f;
  const float sbv = (n < 2) ? scale_b[n] : 0.f;
  const float bmv = (n < 2) ? b_mlp[n]   : 0.f;
  const char* wmlpb = reinterpret_cast<const char*>(WmlpT);
  float tk0[4], tk1[4];
  {
    float e0 = embed[0], e1 = embed[1];
#pragma unroll
    for (int r = 0; r < 4; ++r) { tk0[r] = e0; tk1[r] = e1; }
  }

#pragma unroll 1
  for (int s = 0; s < 35; ++s) {
    const int T = 1024 + s;
    const int parR = T & 1, parW = parR ^ 1;
    POLL(T);
    LOAD_HAO(parR);
    LOAD_HAP(parR);

    if (s > 0) {
      // pred_{s-1} = h(T) @ W_mlp + b_mlp (all waves; reuses ha frags)
      f4 pf; pf[0] = bmv; pf[1] = bmv; pf[2] = bmv; pf[3] = bmv;
#pragma unroll
      for (int i = 0; i < 4; ++i) {
        h8 wb = (n < 2)
            ? *reinterpret_cast<const h8*>(
                  wmlpb + (uint32_t)(n * 512 + quad * 16) + sbO + (uint32_t)(i * 64))
            : z8;
        pf = __builtin_amdgcn_mfma_f32_16x16x32_f16(haO[i], wb, pf, 0, 0, 0);
      }
#pragma unroll
      for (int i = 0; i < 4; ++i) {
        h8 wb = (n < 2)
            ? *reinterpret_cast<const h8*>(
                  wmlpb + (uint32_t)(n * 512 + quad * 16) + sbP + (uint32_t)(i * 64))
            : z8;
        pf = __builtin_amdgcn_mfma_f32_16x16x32_f16(haP[i], wb, pf, 0, 0, 0);
      }
      if (half == 0 && w == 0 && n < 2) {
#pragma unroll
        for (int r = 0; r < 4; ++r)
          out[((size_t)(b0 + quad * 4 + r) * 35 + (s - 1)) * 2 + n] =
              pf[r] * swv + sbv;
      }
      // lane (n,quad) needs tok[row=quad*4+r][e] from lane quad*16+e, reg r
#pragma unroll
      for (int r = 0; r < 4; ++r) {
        tk0[r] = __shfl(pf[r], quad * 16);
        tk1[r] = __shfl(pf[r], quad * 16 + 1);
      }
    }

    f4 acc[4];
#pragma unroll
    for (int g = 0; g < 4; ++g) {
      float dbv = *reinterpret_cast<const float*>(
          &smem[LDB + (uint32_t)(g * 512 + cloc * 4)]);
      float d0v = *reinterpret_cast<const float*>(
          &smem[LD0 + (uint32_t)(g * 512 + cloc * 4)]);
      float d1v = *reinterpret_cast<const float*>(
          &smem[LD1 + (uint32_t)(g * 512 + cloc * 4)]);
#pragma unroll
      for (int r = 0; r < 4; ++r)
        acc[g][r] = dbv + tk0[r] * d0v + tk1[r] * d1v;
    }
    MM_OWN();
    MM_PAR();

    GATES_STORES(parW, T);
  }

  // epilogue: pred_34 from h(1059) (half0 writes out)
  if (half == 0) {
    POLL(1059);
    LOAD_HAO(1);
    LOAD_HAP(1);
    f4 pf; pf[0] = bmv; pf[1] = bmv; pf[2] = bmv; pf[3] = bmv;
#pragma unroll
    for (int i = 0; i < 4; ++i) {
      h8 wb = (n < 2)
          ? *reinterpret_cast<const h8*>(
                wmlpb + (uint32_t)(n * 512 + quad * 16) + sbO + (uint32_t)(i * 64))
          : z8;
      pf = __builtin_amdgcn_mfma_f32_16x16x32_f16(haO[i], wb, pf, 0, 0, 0);
    }
#pragma unroll
    for (int i = 0; i < 4; ++i) {
      h8 wb = (n < 2)
          ? *reinterpret_cast<const h8*>(
                wmlpb + (uint32_t)(n * 512 + quad * 16) + sbP + (uint32_t)(i * 64))
          : z8;
      pf = __builtin_amdgcn_mfma_f32_16x16x32_f16(haP[i], wb, pf, 0, 0, 0);
    }
    if (w == 0 && n < 2) {
#pragma unroll
      for (int r = 0; r < 4; ++r)
        out[((size_t)(b0 + quad * 4 + r) * 35 + 34) * 2 + n] = pf[r] * swv + sbv;
    }
  }
}

extern "C" void kernel_launch(void* const* d_in, const int* in_sizes, int n_in,
                              void* d_out, int out_size, void* d_ws, size_t ws_size,
                              hipStream_t stream) {
  const float* pulse    = (const float*)d_in[0];
  const float* bn_gamma = (const float*)d_in[1];
  const float* bn_beta  = (const float*)d_in[2];
  const float* bn_mean  = (const float*)d_in[3];
  const float* bn_var   = (const float*)d_in[4];
  const float* W_pulse  = (const float*)d_in[5];
  const float* b_pulse  = (const float*)d_in[6];
  const float* lstm_k   = (const float*)d_in[7];
  const float* lstm_rk  = (const float*)d_in[8];
  const float* lstm_b   = (const float*)d_in[9];
  const float* embed    = (const float*)d_in[10];
  const float* W_eis    = (const float*)d_in[11];
  const float* b_eis    = (const float*)d_in[12];
  const float* W_mlp    = (const float*)d_in[13];
  const float* b_mlp    = (const float*)d_in[14];
  const float* scale_w  = (const float*)d_in[15];
  const float* scale_b  = (const float*)d_in[16];

  char* ws = (char*)d_ws;
  uint32_t* flags  = (uint32_t*)(ws + WS_FLAGS);
  uint32_t* hbuf   = (uint32_t*)(ws + WS_HBUF);
  _Float16* rkT    = (_Float16*)(ws + WS_RKT);
  _Float16* WeffT  = (_Float16*)(ws + WS_WEFF);
  _Float16* WmlpT  = (_Float16*)(ws + WS_WMLP);
  float*    Deff   = (float*)(ws + WS_DEFF);
  float*    zbias  = (float*)(ws + WS_ZB);
  float*    dbias  = (float*)(ws + WS_DB);

  // zero flags + h exchange buffer: (2048 + 262144)/4 = 66048 words
  zero_ws_k<<<258, 256, 0, stream>>>((uint32_t*)d_ws, 66048);
  precompute_k<<<1024, 256, 0, stream>>>(bn_gamma, bn_beta, bn_mean, bn_var,
                                         W_pulse, b_pulse, lstm_k, lstm_rk, lstm_b,
                                         W_eis, b_eis, W_mlp,
                                         rkT, WeffT, WmlpT, Deff, zbias, dbias);
  lstm_main_k<<<32, 512, 0, stream>>>(pulse, embed, b_mlp, scale_w, scale_b,
                                      rkT, WeffT, WmlpT, Deff, zbias, dbias,
                                      hbuf, flags, (float*)d_out);
}

// Round 8
// 2847.639 us; speedup vs baseline: 4.4356x; 1.2903x over previous
//
#include <hip/hip_runtime.h>
#include <cstdint>
#include <cstddef>

// ---------------------------------------------------------------------------
// Trainer_91216515433187: BN + Dense + LSTM encoder (1024 steps) + 35-step
// autoregressive LSTM decoder.
//
// Round 9: R8 topology (32 WGs = 16 tiles x 2 hidden-halves, weights
// AGPR-pinned register-resident, own h-half in LDS parity buffers) with a
// WAVE-SPECIALIZED exchange that takes the Infinity-Fabric hops off the
// 8-wave critical path:
//   wave 7 (exporter): LDS own-h -> 4x global_store_dwordx4 sc0 sc1
//     (coalesced, IF-coherent) -> vmcnt drain -> relaxed flag. Drain overlaps
//     waves 0-6 phase-A compute; gates do NO global stores anymore.
//   wave 6 (importer): phase-A first, then poll flag (relaxed) -> 4x
//     global_load_dwordx4 sc0 sc1 -> stage partner half into a partner-LDS
//     mirror (byte-copy layout; all frag addressing shared with own half).
//   sync2 publishes partner LDS; sync1 publishes gates' h(t+1). 2 barriers.
// Decoder: exchange -> sync -> pred (all waves, reuses haO/haP) -> __shfl
// token -> acc init (LDS Deff/dbias) -> MFMAs -> gates. Epilogue does one
// final exchange for pred_34.
// ---------------------------------------------------------------------------

typedef _Float16 h8 __attribute__((ext_vector_type(8)));
typedef float f4 __attribute__((ext_vector_type(4)));

// ws byte offsets
#define WS_FLAGS  0         // 16 tiles x 2 halves x 16 u32 = 2048
#define WS_HBUF   2048      // 2 par x 16 tiles x 2 halves x 4096 B = 262144
#define WS_RKT    264192    // 1024 cols x 256 k f16 = 524288
#define WS_WEFF   788480    // 1024 cols x 8 f f16 = 16384
#define WS_WMLP   804864    // 2 e x 256 k f16 = 1024
#define WS_DEFF   805888    // f32 [2][1024] = 8192
#define WS_ZB     814080    // 1024 f32
#define WS_DB     818176    // 1024 f32  -> end 822272

// LDS layout (24 KB)
#define LB_HO  0            // own h: 2 par x 4096
#define LB_HP  8192         // partner h mirror: 2 par x 4096
#define LZB    16384        // zbias [g4][cloc128] f32 = 2048
#define LDB    18432        // dbias
#define LD0    20480        // Deff0
#define LD1    22528        // Deff1
#define LDS_SZ 24576

__device__ __forceinline__ float fexp2(float x){
#if __has_builtin(__builtin_amdgcn_exp2f)
  return __builtin_amdgcn_exp2f(x);
#else
  return exp2f(x);
#endif
}
__device__ __forceinline__ float frcp(float x){
#if __has_builtin(__builtin_amdgcn_rcpf)
  return __builtin_amdgcn_rcpf(x);
#else
  return 1.f / x;
#endif
}
__device__ __forceinline__ float sigf(float x){
  return frcp(1.f + fexp2(-1.44269504f * x));
}
__device__ __forceinline__ float tanh_f(float x){
  return 2.f * frcp(1.f + fexp2(-2.88539008f * x)) - 1.f;
}

// IF-coherent (cache-bypassing) vector ops — same semantics as relaxed
// agent-scope atomics (sc0 sc1), but coalesced 16 B/lane.
__device__ __forceinline__ void st_b128_sys(uint64_t addr, h8 v){
  asm volatile("global_store_dwordx4 %0, %1, off sc0 sc1"
               :: "v"(addr), "v"(v) : "memory");
}
__device__ __forceinline__ h8 ld_b128_sys(uint64_t addr){
  h8 r;
  asm volatile("global_load_dwordx4 %0, %1, off sc0 sc1"
               : "=v"(r) : "v"(addr) : "memory");
  return r;
}

__global__ void zero_ws_k(uint32_t* __restrict__ p, int nw){
  int i = blockIdx.x * 256 + threadIdx.x;
  if (i < nw) p[i] = 0u;
}

// grid 1024 x 256 threads (known-correct)
__global__ void precompute_k(const float* __restrict__ bn_gamma,
                             const float* __restrict__ bn_beta,
                             const float* __restrict__ bn_mean,
                             const float* __restrict__ bn_var,
                             const float* __restrict__ W_pulse,   // (8,256)
                             const float* __restrict__ b_pulse,   // (256)
                             const float* __restrict__ lstm_k,    // (256,1024)
                             const float* __restrict__ lstm_rk,   // (256,1024)
                             const float* __restrict__ lstm_b,    // (1024)
                             const float* __restrict__ W_eis,     // (2,256)
                             const float* __restrict__ b_eis,     // (256)
                             const float* __restrict__ W_mlp,     // (256,2)
                             _Float16* __restrict__ rkT,          // [col][k]
                             _Float16* __restrict__ WeffT,        // [col][f]
                             _Float16* __restrict__ WmlpT,        // [e][k]
                             float* __restrict__ Deff,            // [e][col]
                             float* __restrict__ zbias,
                             float* __restrict__ dbias)
{
  int gid = blockIdx.x * 256 + threadIdx.x;   // 0..262143
  {
    int col = gid >> 8;
    int k   = gid & 255;
    rkT[col * 256 + k] = (_Float16)lstm_rk[k * 1024 + col];
  }
  if (gid < 512) {
    int e = gid >> 8, k = gid & 255;
    WmlpT[e * 256 + k] = (_Float16)W_mlp[k * 2 + e];
  }
  if (gid < 1024) {
    int j = gid;
    float a[8], bv[8];
#pragma unroll
    for (int f = 0; f < 8; ++f) {
      float af = bn_gamma[f] * rsqrtf(bn_var[f] + 1e-3f);
      a[f]  = af;
      bv[f] = bn_beta[f] - bn_mean[f] * af;
    }
    float m[8] = {0,0,0,0,0,0,0,0};
    float d0 = 0.f, d1 = 0.f, zb2 = 0.f, db2 = 0.f;
    for (int k = 0; k < 256; ++k) {
      float lk = lstm_k[k * 1024 + j];
#pragma unroll
      for (int f = 0; f < 8; ++f) m[f] += W_pulse[f * 256 + k] * lk;
      d0  += W_eis[k]       * lk;
      d1  += W_eis[256 + k] * lk;
      zb2 += b_pulse[k] * lk;
      db2 += b_eis[k]   * lk;
    }
    float zb = lstm_b[j] + zb2;
#pragma unroll
    for (int f = 0; f < 8; ++f) {
      zb += bv[f] * m[f];
      WeffT[j * 8 + f] = (_Float16)(a[f] * m[f]);
    }
    zbias[j] = zb;
    dbias[j] = lstm_b[j] + db2;
    Deff[j]        = d0;
    Deff[1024 + j] = d1;
  }
}

// ---- exchange macros (wave-specialized) ----
// exporter (wave 7): read LDS own h(parity p), issue 4 coalesced IF stores
#define EXPORT_ISSUE(p_)                                                       \
  {                                                                            \
    _Pragma("unroll") for (int i_ = 0; i_ < 4; ++i_) {                         \
      h8 ev = *reinterpret_cast<const h8*>(                                    \
          &smem[LB_HO + (p_) * 4096 + (uint32_t)(lane * 16 + i_ * 1024)]);     \
      st_b128_sys(gme0 + (uint64_t)((uint32_t)(p_) * 131072u +                 \
                                    (uint32_t)(lane * 16 + i_ * 1024)), ev);   \
    }                                                                          \
  }

#define EXPORT_FINISH(fl_)                                                     \
  {                                                                            \
    asm volatile("s_waitcnt vmcnt(0)" ::: "memory");                           \
    if (lane == 0)                                                             \
      __hip_atomic_store(flagMe, (uint32_t)(fl_), __ATOMIC_RELAXED,            \
                         __HIP_MEMORY_SCOPE_AGENT);                            \
  }

// importer (wave 6): poll relaxed flag, pull 4 coalesced IF loads, stage LDS
#define IMPORT(p_, fl_)                                                        \
  {                                                                            \
    while (__hip_atomic_load(flagPa, __ATOMIC_RELAXED,                         \
                             __HIP_MEMORY_SCOPE_AGENT) < (uint32_t)(fl_))      \
      __builtin_amdgcn_s_sleep(1);                                             \
    asm volatile("" ::: "memory");                                             \
    h8 iv0 = ld_b128_sys(gpa0 + (uint64_t)((uint32_t)(p_) * 131072u +          \
                                           (uint32_t)(lane * 16 + 0)));        \
    h8 iv1 = ld_b128_sys(gpa0 + (uint64_t)((uint32_t)(p_) * 131072u +          \
                                           (uint32_t)(lane * 16 + 1024)));     \
    h8 iv2 = ld_b128_sys(gpa0 + (uint64_t)((uint32_t)(p_) * 131072u +          \
                                           (uint32_t)(lane * 16 + 2048)));     \
    h8 iv3 = ld_b128_sys(gpa0 + (uint64_t)((uint32_t)(p_) * 131072u +          \
                                           (uint32_t)(lane * 16 + 3072)));     \
    asm volatile("s_waitcnt vmcnt(0)" ::: "memory");                           \
    *reinterpret_cast<h8*>(&smem[LB_HP + (p_) * 4096 + lane * 16 + 0])    = iv0; \
    *reinterpret_cast<h8*>(&smem[LB_HP + (p_) * 4096 + lane * 16 + 1024]) = iv1; \
    *reinterpret_cast<h8*>(&smem[LB_HP + (p_) * 4096 + lane * 16 + 2048]) = iv2; \
    *reinterpret_cast<h8*>(&smem[LB_HP + (p_) * 4096 + lane * 16 + 3072]) = iv3; \
  }

#define LOAD_HAO(p_)                                                           \
  h8 haO[4];                                                                   \
  _Pragma("unroll") for (int i_ = 0; i_ < 4; ++i_)                             \
    haO[i_] = *reinterpret_cast<const h8*>(                                    \
        &smem[LB_HO + (p_) * 4096 + lrd + (uint32_t)(i_ * 1024)]);

#define LOAD_HAP(p_)                                                           \
  h8 haP[4];                                                                   \
  _Pragma("unroll") for (int i_ = 0; i_ < 4; ++i_)                             \
    haP[i_] = *reinterpret_cast<const h8*>(                                    \
        &smem[LB_HP + (p_) * 4096 + lrd + (uint32_t)(i_ * 1024)]);

#define MM_OWN()                                                               \
  _Pragma("unroll") for (int i_ = 0; i_ < 4; ++i_)                             \
  _Pragma("unroll") for (int g_ = 0; g_ < 4; ++g_)                             \
    acc[g_] = __builtin_amdgcn_mfma_f32_16x16x32_f16(haO[i_], WO[i_][g_],      \
                                                     acc[g_], 0, 0, 0);

#define MM_PAR()                                                               \
  _Pragma("unroll") for (int i_ = 0; i_ < 4; ++i_)                             \
  _Pragma("unroll") for (int g_ = 0; g_ < 4; ++g_)                             \
    acc[g_] = __builtin_amdgcn_mfma_f32_16x16x32_f16(haP[i_], WP[i_][g_],      \
                                                     acc[g_], 0, 0, 0);

// gates -> own-h LDS store (parity pw). No global stores here anymore.
#define GATES_LDS(pw_)                                                         \
  {                                                                            \
    _Float16 hv[4];                                                            \
    _Pragma("unroll") for (int r_ = 0; r_ < 4; ++r_) {                         \
      float iv = sigf(acc[0][r_]);                                             \
      float fv = sigf(acc[1][r_]);                                             \
      float gv = tanh_f(acc[2][r_]);                                           \
      float ov = sigf(acc[3][r_]);                                             \
      float cc = fv * cf[r_] + iv * gv;                                        \
      cf[r_] = cc;                                                             \
      hv[r_] = (_Float16)(ov * tanh_f(cc));                                    \
    }                                                                          \
    _Pragma("unroll") for (int r_ = 0; r_ < 4; ++r_)                           \
      *reinterpret_cast<_Float16*>(                                            \
          &smem[LB_HO + (pw_) * 4096 + lwr + (uint32_t)(r_ * 16)]) = hv[r_];   \
  }

// 32 blocks x 512 threads: block = (tile = bid&15, half = bid>>4)
__global__ __launch_bounds__(512, 2)
void lstm_main_k(const float* __restrict__ pulse,      // (256,1024,8)
                 const float* __restrict__ embed,      // (1,2)
                 const float* __restrict__ b_mlp,      // (2)
                 const float* __restrict__ scale_w,    // (2)
                 const float* __restrict__ scale_b,    // (2)
                 const _Float16* __restrict__ rkT,
                 const _Float16* __restrict__ WeffT,
                 const _Float16* __restrict__ WmlpT,
                 const float* __restrict__ Deff,
                 const float* __restrict__ zbias,
                 const float* __restrict__ dbias,
                 char* __restrict__ hbuf,
                 uint32_t* __restrict__ flags,
                 float* __restrict__ out)              // (256,35,2)
{
  __shared__ alignas(16) char smem[LDS_SZ];

  const int tid  = threadIdx.x;
  const int w    = tid >> 6;
  const int lane = tid & 63;
  const int n    = lane & 15;
  const int quad = lane >> 4;
  const int bid  = blockIdx.x;
  const int tile = bid & 15;
  const int half = bid >> 4;
  const int b0   = tile * 16;
  const int cloc = w * 16 + n;                // local hidden col 0..127
  const int hcol = half * 128 + cloc;         // global hidden col

  // zero own + partner h LDS (16 KB)
  {
    f4 zz; zz[0] = zz[1] = zz[2] = zz[3] = 0.f;
    *reinterpret_cast<f4*>(&smem[tid * 16]) = zz;
    *reinterpret_cast<f4*>(&smem[8192 + tid * 16]) = zz;
  }
  // biases/Deff -> LDS (quad0 lanes cover all cloc)
  if (quad == 0) {
#pragma unroll
    for (int g = 0; g < 4; ++g) {
      int zc = g * 256 + hcol;
      *reinterpret_cast<float*>(&smem[LZB + g * 512 + cloc * 4]) = zbias[zc];
      *reinterpret_cast<float*>(&smem[LDB + g * 512 + cloc * 4]) = dbias[zc];
      *reinterpret_cast<float*>(&smem[LD0 + g * 512 + cloc * 4]) = Deff[zc];
      *reinterpret_cast<float*>(&smem[LD1 + g * 512 + cloc * 4]) = Deff[1024 + zc];
    }
  }

  h8 z8;
#pragma unroll
  for (int j = 0; j < 8; ++j) z8[j] = (_Float16)0.f;

  // ---- recurrent weights: register-resident, AGPR-pinned (R7/R8-proven) ----
  const char* rkTb = reinterpret_cast<const char*>(rkT);
  const uint32_t gbo = (uint32_t)(hcol * 512 + quad * 16);
  const uint32_t sbO = (uint32_t)(half * 256);   // own slot byte base
  const uint32_t sbP = 256u - sbO;               // partner slot byte base
  h8 WO[4][4], WP[4][4];
#pragma unroll
  for (int i = 0; i < 4; ++i)
#pragma unroll
    for (int g = 0; g < 4; ++g) {
      WO[i][g] = *reinterpret_cast<const h8*>(
          rkTb + gbo + (uint32_t)(g * 131072) + sbO + (uint32_t)(i * 64));
      asm("" : "+a"(WO[i][g]));
      WP[i][g] = *reinterpret_cast<const h8*>(
          rkTb + gbo + (uint32_t)(g * 131072) + sbP + (uint32_t)(i * 64));
      asm("" : "+a"(WP[i][g]));
    }
  h8 Wf[4];
#pragma unroll
  for (int g = 0; g < 4; ++g) {
    Wf[g] = (quad == 0)
        ? *reinterpret_cast<const h8*>(WeffT + (size_t)(g * 256 + hcol) * 8)
        : z8;
    asm("" : "+a"(Wf[g]));
  }

  // per-lane addresses
  const uint32_t lrd = (uint32_t)(quad * 256 + n * 16);   // A-frag read
  const uint32_t lwr = (uint32_t)((cloc >> 3) * 256 + quad * 64 + (cloc & 7) * 2);
  const uint64_t hb   = (uint64_t)(uintptr_t)hbuf;
  const uint64_t gme0 = hb + (uint64_t)((tile * 2 + half) * 4096);
  const uint64_t gpa0 = hb + (uint64_t)((tile * 2 + (1 - half)) * 4096);
  uint32_t* flagMe = flags + (tile * 2 + half) * 16;
  uint32_t* flagPa = flags + (tile * 2 + (1 - half)) * 16;

  f4 cf; cf[0] = cf[1] = cf[2] = cf[3] = 0.f;
  const float* prow = pulse + (size_t)(b0 + n) * 8192;    // quad0 lanes

  // prologue: x(0) prefetch
  f4 px0, px1;
  px0[0]=px0[1]=px0[2]=px0[3]=0.f; px1[0]=px1[1]=px1[2]=px1[3]=0.f;
  if (quad == 0) {
    const f4* pp = reinterpret_cast<const f4*>(prow);
    px0 = pp[0]; px1 = pp[1];
  }

  __syncthreads();

  // ---------------- encoder: t = 0..1023 ----------------
#pragma unroll 1
  for (int t = 0; t < 1024; ++t) {
    const int p = t & 1, pw = p ^ 1;

    if (w == 7) EXPORT_ISSUE(p);        // stores fly under phase-A

    // phase A (all waves): acc init + x-affine + own-half MFMAs
    f4 acc[4];
#pragma unroll
    for (int g = 0; g < 4; ++g) {
      float zv = *reinterpret_cast<const float*>(
          &smem[LZB + (uint32_t)(g * 512 + cloc * 4)]);
      acc[g][0] = zv; acc[g][1] = zv; acc[g][2] = zv; acc[g][3] = zv;
    }
    h8 pa = z8;
    if (quad == 0) {
      pa[0] = (_Float16)px0[0]; pa[1] = (_Float16)px0[1];
      pa[2] = (_Float16)px0[2]; pa[3] = (_Float16)px0[3];
      pa[4] = (_Float16)px1[0]; pa[5] = (_Float16)px1[1];
      pa[6] = (_Float16)px1[2]; pa[7] = (_Float16)px1[3];
    }
#pragma unroll
    for (int g = 0; g < 4; ++g)
      acc[g] = __builtin_amdgcn_mfma_f32_16x16x32_f16(pa, Wf[g], acc[g], 0, 0, 0);

    LOAD_HAO(p);
    MM_OWN();

    // x(t+1) prefetch
    if (quad == 0) {
      int tp = (t + 1 < 1024) ? t + 1 : 1023;
      const f4* pp = reinterpret_cast<const f4*>(prow) + tp * 2;
      px0 = pp[0]; px1 = pp[1];
    }

    if (w == 7) EXPORT_FINISH(t + 1);   // drain (overlapped) + flag
    if (w == 6) IMPORT(p, t + 1);       // poll + pull + stage LDS

    __syncthreads();                     // sync2: partner h(t) in LDS

    LOAD_HAP(p);
    MM_PAR();

    GATES_LDS(pw);                       // h(t+1) -> own LDS
    __syncthreads();                     // sync1
  }

  // ---------------- decoder: 35 steps ----------------
  const float swv = (n < 2) ? scale_w[n] : 0.f;
  const float sbv = (n < 2) ? scale_b[n] : 0.f;
  const float bmv = (n < 2) ? b_mlp[n]   : 0.f;
  const char* wmlpb = reinterpret_cast<const char*>(WmlpT);
  float tk0[4], tk1[4];
  {
    float e0 = embed[0], e1 = embed[1];
#pragma unroll
    for (int r = 0; r < 4; ++r) { tk0[r] = e0; tk1[r] = e1; }
  }

#pragma unroll 1
  for (int s = 0; s < 35; ++s) {
    const int T = 1024 + s;
    const int p = T & 1, pw = p ^ 1;

    if (w == 7) { EXPORT_ISSUE(p); EXPORT_FINISH(T + 1); }
    if (w == 6) IMPORT(p, T + 1);
    __syncthreads();                     // h(T) complete in LDS

    LOAD_HAO(p);
    LOAD_HAP(p);

    if (s > 0) {
      // pred_{s-1} = h(T) @ W_mlp + b_mlp (all waves)
      f4 pf; pf[0] = bmv; pf[1] = bmv; pf[2] = bmv; pf[3] = bmv;
#pragma unroll
      for (int i = 0; i < 4; ++i) {
        h8 wb = (n < 2)
            ? *reinterpret_cast<const h8*>(
                  wmlpb + (uint32_t)(n * 512 + quad * 16) + sbO + (uint32_t)(i * 64))
            : z8;
        pf = __builtin_amdgcn_mfma_f32_16x16x32_f16(haO[i], wb, pf, 0, 0, 0);
      }
#pragma unroll
      for (int i = 0; i < 4; ++i) {
        h8 wb = (n < 2)
            ? *reinterpret_cast<const h8*>(
                  wmlpb + (uint32_t)(n * 512 + quad * 16) + sbP + (uint32_t)(i * 64))
            : z8;
        pf = __builtin_amdgcn_mfma_f32_16x16x32_f16(haP[i], wb, pf, 0, 0, 0);
      }
      if (half == 0 && w == 0 && n < 2) {
#pragma unroll
        for (int r = 0; r < 4; ++r)
          out[((size_t)(b0 + quad * 4 + r) * 35 + (s - 1)) * 2 + n] =
              pf[r] * swv + sbv;
      }
#pragma unroll
      for (int r = 0; r < 4; ++r) {
        tk0[r] = __shfl(pf[r], quad * 16);
        tk1[r] = __shfl(pf[r], quad * 16 + 1);
      }
    }

    f4 acc[4];
#pragma unroll
    for (int g = 0; g < 4; ++g) {
      float dbv = *reinterpret_cast<const float*>(
          &smem[LDB + (uint32_t)(g * 512 + cloc * 4)]);
      float d0v = *reinterpret_cast<const float*>(
          &smem[LD0 + (uint32_t)(g * 512 + cloc * 4)]);
      float d1v = *reinterpret_cast<const float*>(
          &smem[LD1 + (uint32_t)(g * 512 + cloc * 4)]);
#pragma unroll
      for (int r = 0; r < 4; ++r)
        acc[g][r] = dbv + tk0[r] * d0v + tk1[r] * d1v;
    }
    MM_OWN();
    MM_PAR();

    GATES_LDS(pw);
    __syncthreads();                     // sync1
  }

  // epilogue: exchange h(1059) (parity 1), then pred_34 (half0 writes out)
  {
    if (w == 7) { EXPORT_ISSUE(1); EXPORT_FINISH(1060); }
    if (w == 6) IMPORT(1, 1060);
    __syncthreads();

    if (half == 0) {
      LOAD_HAO(1);
      LOAD_HAP(1);
      f4 pf; pf[0] = bmv; pf[1] = bmv; pf[2] = bmv; pf[3] = bmv;
#pragma unroll
      for (int i = 0; i < 4; ++i) {
        h8 wb = (n < 2)
            ? *reinterpret_cast<const h8*>(
                  wmlpb + (uint32_t)(n * 512 + quad * 16) + sbO + (uint32_t)(i * 64))
            : z8;
        pf = __builtin_amdgcn_mfma_f32_16x16x32_f16(haO[i], wb, pf, 0, 0, 0);
      }
#pragma unroll
      for (int i = 0; i < 4; ++i) {
        h8 wb = (n < 2)
            ? *reinterpret_cast<const h8*>(
                  wmlpb + (uint32_t)(n * 512 + quad * 16) + sbP + (uint32_t)(i * 64))
            : z8;
        pf = __builtin_amdgcn_mfma_f32_16x16x32_f16(haP[i], wb, pf, 0, 0, 0);
      }
      if (w == 0 && n < 2) {
#pragma unroll
        for (int r = 0; r < 4; ++r)
          out[((size_t)(b0 + quad * 4 + r) * 35 + 34) * 2 + n] = pf[r] * swv + sbv;
      }
    }
  }
}

extern "C" void kernel_launch(void* const* d_in, const int* in_sizes, int n_in,
                              void* d_out, int out_size, void* d_ws, size_t ws_size,
                              hipStream_t stream) {
  const float* pulse    = (const float*)d_in[0];
  const float* bn_gamma = (const float*)d_in[1];
  const float* bn_beta  = (const float*)d_in[2];
  const float* bn_mean  = (const float*)d_in[3];
  const float* bn_var   = (const float*)d_in[4];
  const float* W_pulse  = (const float*)d_in[5];
  const float* b_pulse  = (const float*)d_in[6];
  const float* lstm_k   = (const float*)d_in[7];
  const float* lstm_rk  = (const float*)d_in[8];
  const float* lstm_b   = (const float*)d_in[9];
  const float* embed    = (const float*)d_in[10];
  const float* W_eis    = (const float*)d_in[11];
  const float* b_eis    = (const float*)d_in[12];
  const float* W_mlp    = (const float*)d_in[13];
  const float* b_mlp    = (const float*)d_in[14];
  const float* scale_w  = (const float*)d_in[15];
  const float* scale_b  = (const float*)d_in[16];

  char* ws = (char*)d_ws;
  uint32_t* flags  = (uint32_t*)(ws + WS_FLAGS);
  char*     hbuf   = ws + WS_HBUF;
  _Float16* rkT    = (_Float16*)(ws + WS_RKT);
  _Float16* WeffT  = (_Float16*)(ws + WS_WEFF);
  _Float16* WmlpT  = (_Float16*)(ws + WS_WMLP);
  float*    Deff   = (float*)(ws + WS_DEFF);
  float*    zbias  = (float*)(ws + WS_ZB);
  float*    dbias  = (float*)(ws + WS_DB);

  // zero flags + h exchange buffer: (2048 + 262144)/4 = 66048 words
  zero_ws_k<<<258, 256, 0, stream>>>((uint32_t*)d_ws, 66048);
  precompute_k<<<1024, 256, 0, stream>>>(bn_gamma, bn_beta, bn_mean, bn_var,
                                         W_pulse, b_pulse, lstm_k, lstm_rk, lstm_b,
                                         W_eis, b_eis, W_mlp,
                                         rkT, WeffT, WmlpT, Deff, zbias, dbias);
  lstm_main_k<<<32, 512, 0, stream>>>(pulse, embed, b_mlp, scale_w, scale_b,
                                      rkT, WeffT, WmlpT, Deff, zbias, dbias,
                                      hbuf, flags, (float*)d_out);
}

// Round 9
// 2122.140 us; speedup vs baseline: 5.9520x; 1.3419x over previous
//
#include <hip/hip_runtime.h>
#include <cstdint>
#include <cstddef>

// ---------------------------------------------------------------------------
// Trainer_91216515433187: BN + Dense + LSTM encoder (1024 steps) + 35-step
// autoregressive LSTM decoder.
//
// Round 10: R9 topology (32 WGs = 16 tiles x 2 hidden-halves, recurrent
// weights AGPR-pinned register-resident, own h-half in LDS parity buffers)
// with a TAGGED, FLAG-FREE exchange. Each exchanged h value is one u32
// {tag = step, f16 value} — self-validating atom:
//   * export: gates issue 4 fire-and-forget global_store_dword sc0 sc1
//     (no exporter wave, no vmcnt(0) store-ack, no flag).
//   * import: all 8 waves pull 1KB slices (1 dwordx4/lane, sc0 sc1), check
//     4 tags, retry until __all match, v_perm-extract, stage LDS mirror.
//   * barriers are RAW (s_waitcnt lgkmcnt(0) + s_barrier): pending global
//     stores cross them freely. Two raw barriers per step.
// This removes 2.5 of the 4 serial Infinity-Fabric round-trips per step that
// R9 still paid (store-ack, flag propagate, poll).
// ---------------------------------------------------------------------------

typedef _Float16 h8 __attribute__((ext_vector_type(8)));
typedef float f4 __attribute__((ext_vector_type(4)));
typedef uint32_t ui4 __attribute__((ext_vector_type(4)));

// ws byte offsets
#define WS_HBUF   0         // tagged h: 2 par x 16 tiles x 2 halves x 8192 B = 524288
#define WS_RKT    524288    // 1024 cols x 256 k f16 = 524288
#define WS_WEFF   1048576   // 1024 cols x 8 f f16 = 16384
#define WS_WMLP   1064960   // 2 e x 256 k f16 = 1024
#define WS_DEFF   1065984   // f32 [2][1024] = 8192
#define WS_ZB     1074176   // 1024 f32
#define WS_DB     1078272   // 1024 f32 -> end 1082368

// LDS layout (24 KB)
#define LB_HO  0            // own h: 2 par x 4096
#define LB_HP  8192         // partner h mirror: 2 par x 4096
#define LZB    16384        // zbias [g4][cloc128] f32 = 2048
#define LDB    18432        // dbias
#define LD0    20480        // Deff0
#define LD1    22528        // Deff1
#define LDS_SZ 24576

__device__ __forceinline__ float fexp2(float x){
#if __has_builtin(__builtin_amdgcn_exp2f)
  return __builtin_amdgcn_exp2f(x);
#else
  return exp2f(x);
#endif
}
__device__ __forceinline__ float frcp(float x){
#if __has_builtin(__builtin_amdgcn_rcpf)
  return __builtin_amdgcn_rcpf(x);
#else
  return 1.f / x;
#endif
}
__device__ __forceinline__ float sigf(float x){
  return frcp(1.f + fexp2(-1.44269504f * x));
}
__device__ __forceinline__ float tanh_f(float x){
  return 2.f * frcp(1.f + fexp2(-2.88539008f * x)) - 1.f;
}
__device__ __forceinline__ uint32_t f16bits(_Float16 h){
  union { _Float16 h; uint16_t u; } t; t.h = h; return (uint32_t)t.u;
}

// IF-coherent (cache-bypassing) ops
__device__ __forceinline__ ui4 ld_b128_sys(uint64_t addr){
  ui4 r;
  asm volatile("global_load_dwordx4 %0, %1, off sc0 sc1"
               : "=v"(r) : "v"(addr) : "memory");
  return r;
}
__device__ __forceinline__ void st_b32_sys(uint64_t addr, uint32_t v){
  asm volatile("global_store_dword %0, %1, off sc0 sc1"
               :: "v"(addr), "v"(v) : "memory");
}

// raw barrier: LDS drain only — global stores stay in flight
#define BAR()                                                                  \
  do {                                                                         \
    asm volatile("s_waitcnt lgkmcnt(0)" ::: "memory");                         \
    __builtin_amdgcn_s_barrier();                                              \
    asm volatile("" ::: "memory");                                             \
  } while (0)

__global__ void zero_ws_k(uint32_t* __restrict__ p, int nw){
  int i = blockIdx.x * 256 + threadIdx.x;
  if (i < nw) p[i] = 0u;
}

// grid 1024 x 256 threads (known-correct)
__global__ void precompute_k(const float* __restrict__ bn_gamma,
                             const float* __restrict__ bn_beta,
                             const float* __restrict__ bn_mean,
                             const float* __restrict__ bn_var,
                             const float* __restrict__ W_pulse,   // (8,256)
                             const float* __restrict__ b_pulse,   // (256)
                             const float* __restrict__ lstm_k,    // (256,1024)
                             const float* __restrict__ lstm_rk,   // (256,1024)
                             const float* __restrict__ lstm_b,    // (1024)
                             const float* __restrict__ W_eis,     // (2,256)
                             const float* __restrict__ b_eis,     // (256)
                             const float* __restrict__ W_mlp,     // (256,2)
                             _Float16* __restrict__ rkT,          // [col][k]
                             _Float16* __restrict__ WeffT,        // [col][f]
                             _Float16* __restrict__ WmlpT,        // [e][k]
                             float* __restrict__ Deff,            // [e][col]
                             float* __restrict__ zbias,
                             float* __restrict__ dbias)
{
  int gid = blockIdx.x * 256 + threadIdx.x;   // 0..262143
  {
    int col = gid >> 8;
    int k   = gid & 255;
    rkT[col * 256 + k] = (_Float16)lstm_rk[k * 1024 + col];
  }
  if (gid < 512) {
    int e = gid >> 8, k = gid & 255;
    WmlpT[e * 256 + k] = (_Float16)W_mlp[k * 2 + e];
  }
  if (gid < 1024) {
    int j = gid;
    float a[8], bv[8];
#pragma unroll
    for (int f = 0; f < 8; ++f) {
      float af = bn_gamma[f] * rsqrtf(bn_var[f] + 1e-3f);
      a[f]  = af;
      bv[f] = bn_beta[f] - bn_mean[f] * af;
    }
    float m[8] = {0,0,0,0,0,0,0,0};
    float d0 = 0.f, d1 = 0.f, zb2 = 0.f, db2 = 0.f;
    for (int k = 0; k < 256; ++k) {
      float lk = lstm_k[k * 1024 + j];
#pragma unroll
      for (int f = 0; f < 8; ++f) m[f] += W_pulse[f * 256 + k] * lk;
      d0  += W_eis[k]       * lk;
      d1  += W_eis[256 + k] * lk;
      zb2 += b_pulse[k] * lk;
      db2 += b_eis[k]   * lk;
    }
    float zb = lstm_b[j] + zb2;
#pragma unroll
    for (int f = 0; f < 8; ++f) {
      zb += bv[f] * m[f];
      WeffT[j * 8 + f] = (_Float16)(a[f] * m[f]);
    }
    zbias[j] = zb;
    dbias[j] = lstm_b[j] + db2;
    Deff[j]        = d0;
    Deff[1024 + j] = d1;
  }
}

// tagged import: this wave's 1KB slice of partner half; retry until all
// 4 tags match Texp; extract f16s; stage LDS mirror (layout = own-h layout).
#define IMPORT(p_, Texp_)                                                      \
  {                                                                            \
    const uint64_t ib = gpa + (uint64_t)((uint32_t)(p_) * 262144u + ioff);     \
    const uint32_t te = (uint32_t)(Texp_);                                     \
    ui4 iv;                                                                    \
    while (true) {                                                             \
      iv = ld_b128_sys(ib);                                                    \
      asm volatile("s_waitcnt vmcnt(0)" ::: "memory");                         \
      __builtin_amdgcn_sched_barrier(0);                                       \
      bool ok = ((iv[0] >> 16) == te) && ((iv[1] >> 16) == te) &&              \
                ((iv[2] >> 16) == te) && ((iv[3] >> 16) == te);                \
      if (__all(ok)) break;                                                    \
    }                                                                          \
    uint32_t pk0 = __builtin_amdgcn_perm(iv[1], iv[0], 0x05040100u);           \
    uint32_t pk1 = __builtin_amdgcn_perm(iv[3], iv[2], 0x05040100u);           \
    const uint32_t lo_ = (uint32_t)(LB_HP + (p_) * 4096) + (ioff >> 1);        \
    *reinterpret_cast<uint32_t*>(&smem[lo_])     = pk0;                        \
    *reinterpret_cast<uint32_t*>(&smem[lo_ + 4]) = pk1;                        \
  }

#define LOAD_HAO(p_)                                                           \
  h8 haO[4];                                                                   \
  _Pragma("unroll") for (int i_ = 0; i_ < 4; ++i_)                             \
    haO[i_] = *reinterpret_cast<const h8*>(                                    \
        &smem[LB_HO + (p_) * 4096 + lrd + (uint32_t)(i_ * 1024)]);

#define LOAD_HAP(p_)                                                           \
  h8 haP[4];                                                                   \
  _Pragma("unroll") for (int i_ = 0; i_ < 4; ++i_)                             \
    haP[i_] = *reinterpret_cast<const h8*>(                                    \
        &smem[LB_HP + (p_) * 4096 + lrd + (uint32_t)(i_ * 1024)]);

#define MM_OWN()                                                               \
  _Pragma("unroll") for (int i_ = 0; i_ < 4; ++i_)                             \
  _Pragma("unroll") for (int g_ = 0; g_ < 4; ++g_)                             \
    acc[g_] = __builtin_amdgcn_mfma_f32_16x16x32_f16(haO[i_], WO[i_][g_],      \
                                                     acc[g_], 0, 0, 0);

#define MM_PAR()                                                               \
  _Pragma("unroll") for (int i_ = 0; i_ < 4; ++i_)                             \
  _Pragma("unroll") for (int g_ = 0; g_ < 4; ++g_)                             \
    acc[g_] = __builtin_amdgcn_mfma_f32_16x16x32_f16(haP[i_], WP[i_][g_],      \
                                                     acc[g_], 0, 0, 0);

// gates -> own-h LDS (parity pw) + 4 fire-and-forget tagged global stores
#define GATES_STORES(pw_, Twr_)                                                \
  {                                                                            \
    _Float16 hv[4];                                                            \
    _Pragma("unroll") for (int r_ = 0; r_ < 4; ++r_) {                         \
      float iv = sigf(acc[0][r_]);                                             \
      float fv = sigf(acc[1][r_]);                                             \
      float gv = tanh_f(acc[2][r_]);                                           \
      float ov = sigf(acc[3][r_]);                                             \
      float cc = fv * cf[r_] + iv * gv;                                        \
      cf[r_] = cc;                                                             \
      hv[r_] = (_Float16)(ov * tanh_f(cc));                                    \
    }                                                                          \
    const uint64_t gw = gme + (uint64_t)((uint32_t)(pw_) * 262144u + 2u * lwr);\
    const uint32_t thi = ((uint32_t)(Twr_)) << 16;                             \
    _Pragma("unroll") for (int r_ = 0; r_ < 4; ++r_) {                         \
      st_b32_sys(gw + (uint64_t)(r_ * 32), thi | f16bits(hv[r_]));             \
      *reinterpret_cast<_Float16*>(                                            \
          &smem[LB_HO + (pw_) * 4096 + lwr + (uint32_t)(r_ * 16)]) = hv[r_];   \
    }                                                                          \
  }

// 32 blocks x 512 threads: block = (tile = bid&15, half = bid>>4)
__global__ __launch_bounds__(512, 2)
void lstm_main_k(const float* __restrict__ pulse,      // (256,1024,8)
                 const float* __restrict__ embed,      // (1,2)
                 const float* __restrict__ b_mlp,      // (2)
                 const float* __restrict__ scale_w,    // (2)
                 const float* __restrict__ scale_b,    // (2)
                 const _Float16* __restrict__ rkT,
                 const _Float16* __restrict__ WeffT,
                 const _Float16* __restrict__ WmlpT,
                 const float* __restrict__ Deff,
                 const float* __restrict__ zbias,
                 const float* __restrict__ dbias,
                 char* __restrict__ hbuf,              // tagged exchange
                 float* __restrict__ out)              // (256,35,2)
{
  __shared__ alignas(16) char smem[LDS_SZ];

  const int tid  = threadIdx.x;
  const int w    = tid >> 6;
  const int lane = tid & 63;
  const int n    = lane & 15;
  const int quad = lane >> 4;
  const int bid  = blockIdx.x;
  const int tile = bid & 15;
  const int half = bid >> 4;
  const int b0   = tile * 16;
  const int cloc = w * 16 + n;                // local hidden col 0..127
  const int hcol = half * 128 + cloc;         // global hidden col

  // zero own + partner h LDS (16 KB)
  {
    f4 zz; zz[0] = zz[1] = zz[2] = zz[3] = 0.f;
    *reinterpret_cast<f4*>(&smem[tid * 16]) = zz;
    *reinterpret_cast<f4*>(&smem[8192 + tid * 16]) = zz;
  }
  // biases/Deff -> LDS (quad0 lanes cover all cloc)
  if (quad == 0) {
#pragma unroll
    for (int g = 0; g < 4; ++g) {
      int zc = g * 256 + hcol;
      *reinterpret_cast<float*>(&smem[LZB + g * 512 + cloc * 4]) = zbias[zc];
      *reinterpret_cast<float*>(&smem[LDB + g * 512 + cloc * 4]) = dbias[zc];
      *reinterpret_cast<float*>(&smem[LD0 + g * 512 + cloc * 4]) = Deff[zc];
      *reinterpret_cast<float*>(&smem[LD1 + g * 512 + cloc * 4]) = Deff[1024 + zc];
    }
  }

  h8 z8;
#pragma unroll
  for (int j = 0; j < 8; ++j) z8[j] = (_Float16)0.f;

  // ---- recurrent weights: register-resident, AGPR-pinned (R7/R8-proven) ----
  const char* rkTb = reinterpret_cast<const char*>(rkT);
  const uint32_t gbo = (uint32_t)(hcol * 512 + quad * 16);
  const uint32_t sbO = (uint32_t)(half * 256);   // own slot byte base
  const uint32_t sbP = 256u - sbO;               // partner slot byte base
  h8 WO[4][4], WP[4][4];
#pragma unroll
  for (int i = 0; i < 4; ++i)
#pragma unroll
    for (int g = 0; g < 4; ++g) {
      WO[i][g] = *reinterpret_cast<const h8*>(
          rkTb + gbo + (uint32_t)(g * 131072) + sbO + (uint32_t)(i * 64));
      asm("" : "+a"(WO[i][g]));
      WP[i][g] = *reinterpret_cast<const h8*>(
          rkTb + gbo + (uint32_t)(g * 131072) + sbP + (uint32_t)(i * 64));
      asm("" : "+a"(WP[i][g]));
    }
  h8 Wf[4];
#pragma unroll
  for (int g = 0; g < 4; ++g) {
    Wf[g] = (quad == 0)
        ? *reinterpret_cast<const h8*>(WeffT + (size_t)(g * 256 + hcol) * 8)
        : z8;
    asm("" : "+a"(Wf[g]));
  }

  // per-lane addresses
  const uint32_t lrd  = (uint32_t)(quad * 256 + n * 16);   // A-frag read
  const uint32_t lwr  = (uint32_t)((cloc >> 3) * 256 + quad * 64 + (cloc & 7) * 2);
  const uint32_t ioff = (uint32_t)(w * 1024 + lane * 16);  // tagged import slice
  const uint64_t hb   = (uint64_t)(uintptr_t)hbuf;
  const uint64_t gme  = hb + (uint64_t)((tile * 2 + half) * 8192);
  const uint64_t gpa  = hb + (uint64_t)((tile * 2 + (1 - half)) * 8192);

  f4 cf; cf[0] = cf[1] = cf[2] = cf[3] = 0.f;
  const float* prow = pulse + (size_t)(b0 + n) * 8192;    // quad0 lanes

  // prologue: x(0) prefetch
  f4 px0, px1;
  px0[0]=px0[1]=px0[2]=px0[3]=0.f; px1[0]=px1[1]=px1[2]=px1[3]=0.f;
  if (quad == 0) {
    const f4* pp = reinterpret_cast<const f4*>(prow);
    px0 = pp[0]; px1 = pp[1];
  }

  __syncthreads();

  // ---------------- encoder: t = 0..1023 ----------------
#pragma unroll 1
  for (int t = 0; t < 1024; ++t) {
    const int p = t & 1, pw = p ^ 1;

    // phase A (all waves): acc init + x-affine + own-half MFMAs
    f4 acc[4];
#pragma unroll
    for (int g = 0; g < 4; ++g) {
      float zv = *reinterpret_cast<const float*>(
          &smem[LZB + (uint32_t)(g * 512 + cloc * 4)]);
      acc[g][0] = zv; acc[g][1] = zv; acc[g][2] = zv; acc[g][3] = zv;
    }
    h8 pa = z8;
    if (quad == 0) {
      pa[0] = (_Float16)px0[0]; pa[1] = (_Float16)px0[1];
      pa[2] = (_Float16)px0[2]; pa[3] = (_Float16)px0[3];
      pa[4] = (_Float16)px1[0]; pa[5] = (_Float16)px1[1];
      pa[6] = (_Float16)px1[2]; pa[7] = (_Float16)px1[3];
    }
#pragma unroll
    for (int g = 0; g < 4; ++g)
      acc[g] = __builtin_amdgcn_mfma_f32_16x16x32_f16(pa, Wf[g], acc[g], 0, 0, 0);

    LOAD_HAO(p);
    MM_OWN();

    // x(t+1) prefetch
    if (quad == 0) {
      int tp = (t + 1 < 1024) ? t + 1 : 1023;
      const f4* pp = reinterpret_cast<const f4*>(prow) + tp * 2;
      px0 = pp[0]; px1 = pp[1];
    }

    IMPORT(p, t);                        // tagged pull, all waves
    BAR();                               // partner h(t) staged in mirror

    LOAD_HAP(p);
    MM_PAR();

    GATES_STORES(pw, t + 1);             // LDS own h(t+1) + tagged export
    BAR();
  }

  // ---------------- decoder: 35 steps ----------------
  const float swv = (n < 2) ? scale_w[n] : 0.f;
  const float sbv = (n < 2) ? scale_b[n] : 0.f;
  const float bmv = (n < 2) ? b_mlp[n]   : 0.f;
  const char* wmlpb = reinterpret_cast<const char*>(WmlpT);
  float tk0[4], tk1[4];
  {
    float e0 = embed[0], e1 = embed[1];
#pragma unroll
    for (int r = 0; r < 4; ++r) { tk0[r] = e0; tk1[r] = e1; }
  }

#pragma unroll 1
  for (int s = 0; s < 35; ++s) {
    const int T = 1024 + s;
    const int p = T & 1, pw = p ^ 1;

    IMPORT(p, T);
    BAR();                               // h(T) complete in LDS

    LOAD_HAO(p);
    LOAD_HAP(p);

    if (s > 0) {
      // pred_{s-1} = h(T) @ W_mlp + b_mlp (all waves)
      f4 pf; pf[0] = bmv; pf[1] = bmv; pf[2] = bmv; pf[3] = bmv;
#pragma unroll
      for (int i = 0; i < 4; ++i) {
        h8 wb = (n < 2)
            ? *reinterpret_cast<const h8*>(
                  wmlpb + (uint32_t)(n * 512 + quad * 16) + sbO + (uint32_t)(i * 64))
            : z8;
        pf = __builtin_amdgcn_mfma_f32_16x16x32_f16(haO[i], wb, pf, 0, 0, 0);
      }
#pragma unroll
      for (int i = 0; i < 4; ++i) {
        h8 wb = (n < 2)
            ? *reinterpret_cast<const h8*>(
                  wmlpb + (uint32_t)(n * 512 + quad * 16) + sbP + (uint32_t)(i * 64))
            : z8;
        pf = __builtin_amdgcn_mfma_f32_16x16x32_f16(haP[i], wb, pf, 0, 0, 0);
      }
      if (half == 0 && w == 0 && n < 2) {
#pragma unroll
        for (int r = 0; r < 4; ++r)
          out[((size_t)(b0 + quad * 4 + r) * 35 + (s - 1)) * 2 + n] =
              pf[r] * swv + sbv;
      }
#pragma unroll
      for (int r = 0; r < 4; ++r) {
        tk0[r] = __shfl(pf[r], quad * 16);
        tk1[r] = __shfl(pf[r], quad * 16 + 1);
      }
    }

    f4 acc[4];
#pragma unroll
    for (int g = 0; g < 4; ++g) {
      float dbv = *reinterpret_cast<const float*>(
          &smem[LDB + (uint32_t)(g * 512 + cloc * 4)]);
      float d0v = *reinterpret_cast<const float*>(
          &smem[LD0 + (uint32_t)(g * 512 + cloc * 4)]);
      float d1v = *reinterpret_cast<const float*>(
          &smem[LD1 + (uint32_t)(g * 512 + cloc * 4)]);
#pragma unroll
      for (int r = 0; r < 4; ++r)
        acc[g][r] = dbv + tk0[r] * d0v + tk1[r] * d1v;
    }
    MM_OWN();
    MM_PAR();

    GATES_STORES(pw, T + 1);
    BAR();
  }

  // epilogue: import h(1059) (parity 1, tag 1059), then pred_34 (half0 out)
  {
    IMPORT(1, 1059);
    BAR();

    if (half == 0) {
      LOAD_HAO(1);
      LOAD_HAP(1);
      f4 pf; pf[0] = bmv; pf[1] = bmv; pf[2] = bmv; pf[3] = bmv;
#pragma unroll
      for (int i = 0; i < 4; ++i) {
        h8 wb = (n < 2)
            ? *reinterpret_cast<const h8*>(
                  wmlpb + (uint32_t)(n * 512 + quad * 16) + sbO + (uint32_t)(i * 64))
            : z8;
        pf = __builtin_amdgcn_mfma_f32_16x16x32_f16(haO[i], wb, pf, 0, 0, 0);
      }
#pragma unroll
      for (int i = 0; i < 4; ++i) {
        h8 wb = (n < 2)
            ? *reinterpret_cast<const h8*>(
                  wmlpb + (uint32_t)(n * 512 + quad * 16) + sbP + (uint32_t)(i * 64))
            : z8;
        pf = __builtin_amdgcn_mfma_f32_16x16x32_f16(haP[i], wb, pf, 0, 0, 0);
      }
      if (w == 0 && n < 2) {
#pragma unroll
        for (int r = 0; r < 4; ++r)
          out[((size_t)(b0 + quad * 4 + r) * 35 + 34) * 2 + n] = pf[r] * swv + sbv;
      }
    }
  }
}

extern "C" void kernel_launch(void* const* d_in, const int* in_sizes, int n_in,
                              void* d_out, int out_size, void* d_ws, size_t ws_size,
                              hipStream_t stream) {
  const float* pulse    = (const float*)d_in[0];
  const float* bn_gamma = (const float*)d_in[1];
  const float* bn_beta  = (const float*)d_in[2];
  const float* bn_mean  = (const float*)d_in[3];
  const float* bn_var   = (const float*)d_in[4];
  const float* W_pulse  = (const float*)d_in[5];
  const float* b_pulse  = (const float*)d_in[6];
  const float* lstm_k   = (const float*)d_in[7];
  const float* lstm_rk  = (const float*)d_in[8];
  const float* lstm_b   = (const float*)d_in[9];
  const float* embed    = (const float*)d_in[10];
  const float* W_eis    = (const float*)d_in[11];
  const float* b_eis    = (const float*)d_in[12];
  const float* W_mlp    = (const float*)d_in[13];
  const float* b_mlp    = (const float*)d_in[14];
  const float* scale_w  = (const float*)d_in[15];
  const float* scale_b  = (const float*)d_in[16];

  char* ws = (char*)d_ws;
  char*     hbuf   = ws + WS_HBUF;
  _Float16* rkT    = (_Float16*)(ws + WS_RKT);
  _Float16* WeffT  = (_Float16*)(ws + WS_WEFF);
  _Float16* WmlpT  = (_Float16*)(ws + WS_WMLP);
  float*    Deff   = (float*)(ws + WS_DEFF);
  float*    zbias  = (float*)(ws + WS_ZB);
  float*    dbias  = (float*)(ws + WS_DB);

  // zero tagged h exchange buffer: 524288/4 = 131072 words (tag 0 = step-0 valid)
  zero_ws_k<<<512, 256, 0, stream>>>((uint32_t*)d_ws, 131072);
  precompute_k<<<1024, 256, 0, stream>>>(bn_gamma, bn_beta, bn_mean, bn_var,
                                         W_pulse, b_pulse, lstm_k, lstm_rk, lstm_b,
                                         W_eis, b_eis, W_mlp,
                                         rkT, WeffT, WmlpT, Deff, zbias, dbias);
  lstm_main_k<<<32, 512, 0, stream>>>(pulse, embed, b_mlp, scale_w, scale_b,
                                      rkT, WeffT, WmlpT, Deff, zbias, dbias,
                                      hbuf, (float*)d_out);
}